// Round 1
// baseline (716.345 us; speedup 1.0000x reference)
//
#include <hip/hip_runtime.h>
#include <math.h>

#define B_SZ   64
#define T_SZ   512
#define DOBS   128
#define DLAT   16
#define DHID   256
#define K_SZ   8
#define ROWS_T 32704   // B*(T-1)

#define LOG2PI_F 1.8378770664093453f
#define VAR_F    5.0e-4f

// ws float offsets
#define LINV0_OFF   16
#define LOGDET0_OFF 2064
#define LINVT_OFF   2080
#define LOGDETT_OFF 4128
// ws[0]=recon_sum ws[1]=logq_sum ws[2]=msm_sum

#define Z_OUT_OFF   4194304   // B*T*DOBS
#define LOSS_OFF    4718592   // + B*T*DLAT

__device__ __forceinline__ float leakyf(float v) { return v > 0.f ? v : 0.01f * v; }
__device__ __forceinline__ float softplusf(float v) {
  return fmaxf(v, 0.f) + log1pf(__expf(-fabsf(v)));
}
__device__ __forceinline__ float dot4(float4 a, float4 b) {
  return a.x*b.x + a.y*b.y + a.z*b.z + a.w*b.w;
}
__device__ __forceinline__ void axpy4(float4& a, float s, float4 b) {
  a.x += s*b.x; a.y += s*b.y; a.z += s*b.z; a.w += s*b.w;
}

// ---------------------------------------------------------------------------
// prep: per-k Cholesky of C C^T + 1e-6 I, then Linv (lower-tri inverse), logdet.
// job<8: init_cov[k] -> LINV0/LOGDET0 ; job>=8: covs[k-8] -> LINVT/LOGDETT
// ---------------------------------------------------------------------------
__global__ __launch_bounds__(256) void prep_kernel(const float* __restrict__ init_cov,
                                                   const float* __restrict__ covs,
                                                   float* __restrict__ ws) {
  __shared__ float M[16][16];
  __shared__ float L[16][16];
  __shared__ float X[16][17];
  int job = blockIdx.x;
  const float* C = (job < 8) ? (init_cov + job * 256) : (covs + (job - 8) * 256);
  float* linv = ws + ((job < 8) ? (LINV0_OFF + job * 256) : (LINVT_OFF + (job - 8) * 256));
  float* logdet = ws + ((job < 8) ? (LOGDET0_OFF + job) : (LOGDETT_OFF + (job - 8)));
  int tid = threadIdx.x;
  int i = tid >> 4, j = tid & 15;
  {
    float s = (i == j) ? 1e-6f : 0.f;
    #pragma unroll
    for (int p = 0; p < 16; ++p) s += C[i * 16 + p] * C[j * 16 + p];
    M[i][j] = s;
  }
  __syncthreads();
  for (int c = 0; c < 16; ++c) {
    if (tid == 0) {
      float s = M[c][c];
      for (int p = 0; p < c; ++p) s -= L[c][p] * L[c][p];
      L[c][c] = sqrtf(s);
    }
    __syncthreads();
    if (tid > c && tid < 16) {
      float s = M[tid][c];
      for (int p = 0; p < c; ++p) s -= L[tid][p] * L[c][p];
      L[tid][c] = s / L[c][c];
    }
    __syncthreads();
  }
  if (tid < 16) {  // column tid of Linv via forward substitution
    for (int r = 0; r < 16; ++r) {
      float s = (r == tid) ? 1.f : 0.f;
      for (int p = tid; p < r; ++p) s -= L[r][p] * X[p][tid];
      X[r][tid] = (r >= tid) ? s / L[r][r] : 0.f;
    }
  }
  __syncthreads();
  linv[i * 16 + j] = X[i][j];
  if (tid == 0) {
    float s = 0.f;
    for (int d = 0; d < 16; ++d) s += logf(L[d][d]);
    *logdet = 2.f * s;
  }
}

// ---------------------------------------------------------------------------
// encoder: h = leaky(x@W1+b1); enc = h@W2+b2; z = mu + exp(.5 lv)*eps; logq acc
// block = 16 rows, 256 threads
// ---------------------------------------------------------------------------
__global__ __launch_bounds__(256) void enc_kernel(
    const float* __restrict__ x, const float* __restrict__ eps,
    const float* __restrict__ W1, const float* __restrict__ b1,
    const float* __restrict__ W2, const float* __restrict__ b2,
    float* __restrict__ z_out, float* __restrict__ ws) {
  __shared__ __align__(16) float xT[128][20];
  __shared__ __align__(16) float hs[16][260];
  __shared__ float sred;
  int tid = threadIdx.x;
  long row0 = (long)blockIdx.x * 16;
  if (tid == 0) sred = 0.f;
  const float* xblk = x + row0 * DOBS;
  #pragma unroll
  for (int q = 0; q < 8; ++q) {
    int e = tid + q * 256;
    xT[e & 127][e >> 7] = xblk[e];
  }
  __syncthreads();
  int tr = tid >> 6, tc = tid & 63;
  float acc[4][4];
  #pragma unroll
  for (int rr = 0; rr < 4; ++rr)
    #pragma unroll
    for (int cc = 0; cc < 4; ++cc) acc[rr][cc] = 0.f;
  #pragma unroll 4
  for (int d = 0; d < 128; ++d) {
    float4 av = *(const float4*)&xT[d][4 * tr];
    float4 bv = *(const float4*)&W1[d * 256 + 4 * tc];
    float am[4] = {av.x, av.y, av.z, av.w};
    float bm[4] = {bv.x, bv.y, bv.z, bv.w};
    #pragma unroll
    for (int rr = 0; rr < 4; ++rr)
      #pragma unroll
      for (int cc = 0; cc < 4; ++cc) acc[rr][cc] += am[rr] * bm[cc];
  }
  {
    float4 b1v = *(const float4*)&b1[4 * tc];
    float bm[4] = {b1v.x, b1v.y, b1v.z, b1v.w};
    #pragma unroll
    for (int rr = 0; rr < 4; ++rr)
      #pragma unroll
      for (int cc = 0; cc < 4; ++cc)
        hs[4 * tr + rr][4 * tc + cc] = leakyf(acc[rr][cc] + bm[cc]);
  }
  __syncthreads();
  // phase C: enc row r, cols c and c+16
  int r = tid >> 4, c = tid & 15;
  float e0 = b2[c], e1 = b2[c + 16];
  const float* W2c = W2 + c;
  #pragma unroll 2
  for (int i4 = 0; i4 < 64; ++i4) {
    float4 h = *(const float4*)&hs[r][4 * i4];
    int ib = i4 * 128;
    e0 += h.x * W2c[ib];      e1 += h.x * W2c[ib + 16];
    e0 += h.y * W2c[ib + 32]; e1 += h.y * W2c[ib + 48];
    e0 += h.z * W2c[ib + 64]; e1 += h.z * W2c[ib + 80];
    e0 += h.w * W2c[ib + 96]; e1 += h.w * W2c[ib + 112];
  }
  long rowg = row0 + r;
  float epsv = eps[rowg * 16 + c];
  float zv = e0 + expf(0.5f * e1) * epsv;
  z_out[rowg * 16 + c] = zv;
  float zz = zv - e0;
  float contrib = e1 + zz * zz * expf(-e1);
  contrib += __shfl_xor(contrib, 1, 64);
  contrib += __shfl_xor(contrib, 2, 64);
  contrib += __shfl_xor(contrib, 4, 64);
  contrib += __shfl_xor(contrib, 8, 64);
  if (c == 0) atomicAdd(&sred, -0.5f * (16.f * LOG2PI_F + contrib));
  __syncthreads();
  if (tid == 0) atomicAdd(&ws[1], sred);
}

// ---------------------------------------------------------------------------
// ev0: ev[b,0,k] from init_mean / Linv0
// ---------------------------------------------------------------------------
__global__ __launch_bounds__(256) void ev0_kernel(const float* __restrict__ z,
                                                  const float* __restrict__ init_mean,
                                                  const float* __restrict__ ws,
                                                  float* __restrict__ ev) {
  int gid = blockIdx.x * 256 + threadIdx.x;
  if (gid >= B_SZ * K_SZ) return;
  int k = gid & 7, b = gid >> 3;
  const float* zr = z + (long)b * T_SZ * 16;
  const float* linv = ws + LINV0_OFF + k * 256;
  float diff[16];
  #pragma unroll
  for (int d = 0; d < 16; ++d) diff[d] = zr[d] - init_mean[k * 16 + d];
  float quad = 0.f;
  #pragma unroll
  for (int i2 = 0; i2 < 16; ++i2) {
    float s = 0.f;
    #pragma unroll
    for (int jj = 0; jj < 16; ++jj) s += linv[i2 * 16 + jj] * diff[jj];
    quad += s * s;
  }
  ev[(long)b * T_SZ * 8 + k] = -0.5f * (16.f * LOG2PI_F + ws[LOGDET0_OFF + k] + quad);
}

// ---------------------------------------------------------------------------
// evt: transition MLP + mvn logprob. grid (32, 8), 512 threads.
// block = 1024 rows of one k; thread half ih handles 128 hidden units;
// 4 rows per thread; partial means exchanged through LDS in 4 stages.
// ---------------------------------------------------------------------------
__global__ __launch_bounds__(512, 2) void evt_kernel(
    const float* __restrict__ z, const float* __restrict__ Wt1,
    const float* __restrict__ bt1, const float* __restrict__ Wt2,
    const float* __restrict__ bt2, const float* __restrict__ ws,
    float* __restrict__ ev) {
  __shared__ __align__(16) float w1t[256][16];   // [i][d] = Wt1[k][d][i]
  __shared__ __align__(16) float w2s[256][16];   // [i][d2]
  __shared__ float bt1s[256];
  __shared__ __align__(16) float linvs[256];
  __shared__ float mbuf[256][17];
  int tid = threadIdx.x;
  int k = blockIdx.y;
  for (int e = tid; e < 4096; e += 512) w1t[e & 255][e >> 8] = Wt1[k * 4096 + e];
  for (int e = tid; e < 4096; e += 512) w2s[e >> 4][e & 15] = Wt2[k * 4096 + e];
  if (tid < 256) bt1s[tid] = bt1[k * 256 + tid];
  if (tid >= 256) linvs[tid - 256] = ws[LINVT_OFF + k * 256 + (tid - 256)];
  float logdetk = ws[LOGDETT_OFF + k];
  __syncthreads();
  int ih = tid >> 8, tl = tid & 255;
  int r0 = blockIdx.x * 1024 + tl * 4;
  float4 zp[4][4];
  #pragma unroll
  for (int rr = 0; rr < 4; ++rr) {
    int r = r0 + rr;
    if (r < ROWS_T) {
      int b = r / 511, tp = r % 511;
      const float4* zr = (const float4*)(z + ((long)(b * 512 + tp)) * 16);
      zp[rr][0] = zr[0]; zp[rr][1] = zr[1]; zp[rr][2] = zr[2]; zp[rr][3] = zr[3];
    } else {
      zp[rr][0] = zp[rr][1] = zp[rr][2] = zp[rr][3] = make_float4(0.f, 0.f, 0.f, 0.f);
    }
  }
  float4 mean[4][4];
  #pragma unroll
  for (int rr = 0; rr < 4; ++rr)
    #pragma unroll
    for (int q = 0; q < 4; ++q) mean[rr][q] = make_float4(0.f, 0.f, 0.f, 0.f);

  #pragma unroll 2
  for (int ii = 0; ii < 128; ++ii) {
    int i = (ih << 7) + ii;
    const float4* wr = (const float4*)&w1t[i][0];
    float4 w0 = wr[0], w1_ = wr[1], w2_ = wr[2], w3_ = wr[3];
    float bti = bt1s[i];
    float s[4];
    #pragma unroll
    for (int rr = 0; rr < 4; ++rr) {
      float a = bti + dot4(zp[rr][0], w0) + dot4(zp[rr][1], w1_)
                    + dot4(zp[rr][2], w2_) + dot4(zp[rr][3], w3_);
      s[rr] = softplusf(a);
    }
    const float4* vr = (const float4*)&w2s[i][0];
    float4 v0 = vr[0], v1 = vr[1], v2 = vr[2], v3 = vr[3];
    #pragma unroll
    for (int rr = 0; rr < 4; ++rr) {
      axpy4(mean[rr][0], s[rr], v0);
      axpy4(mean[rr][1], s[rr], v1);
      axpy4(mean[rr][2], s[rr], v2);
      axpy4(mean[rr][3], s[rr], v3);
    }
  }
  // exchange partial means: half 0 -> half 1, one row-slot per stage
  #pragma unroll
  for (int st = 0; st < 4; ++st) {
    __syncthreads();
    if (ih == 0) {
      float* mb = &mbuf[tl][0];
      const float* mp = (const float*)&mean[st][0];
      #pragma unroll
      for (int d = 0; d < 16; ++d) mb[d] = mp[d];
    }
    __syncthreads();
    if (ih == 1) {
      const float* mb = &mbuf[tl][0];
      float* mp = (float*)&mean[st][0];
      #pragma unroll
      for (int d = 0; d < 16; ++d) mp[d] += mb[d];
    }
  }
  if (ih == 1) {
    const float4* b2p = (const float4*)(bt2 + k * 16);
    float4 bv[4] = {b2p[0], b2p[1], b2p[2], b2p[3]};
    const float* ba = (const float*)bv;
    #pragma unroll
    for (int rr = 0; rr < 4; ++rr) {
      int r = r0 + rr;
      if (r >= ROWS_T) continue;
      int b = r / 511, tp = r % 511, t = tp + 1;
      const float4* zc4 = (const float4*)(z + ((long)(b * 512 + t)) * 16);
      float4 zl[4] = {zc4[0], zc4[1], zc4[2], zc4[3]};
      const float* zc = (const float*)zl;
      const float* mp = (const float*)&mean[rr][0];
      float4 df[4];
      float* dfa = (float*)df;
      #pragma unroll
      for (int d = 0; d < 16; ++d) dfa[d] = zc[d] - (mp[d] + ba[d]);
      float quad = 0.f;
      #pragma unroll
      for (int i2 = 0; i2 < 16; ++i2) {
        const float4* lr = (const float4*)&linvs[i2 * 16];
        float s2 = dot4(lr[0], df[0]) + dot4(lr[1], df[1])
                 + dot4(lr[2], df[2]) + dot4(lr[3], df[3]);
        quad += s2 * s2;
      }
      ev[((long)(b * 512 + t)) * 8 + k] = -0.5f * (16.f * LOG2PI_F + logdetk + quad);
    }
  }
}

// ---------------------------------------------------------------------------
// HMM forward: one wave per batch b; lane = (i,j) in 8x8. 4 blocks x 1024.
// ---------------------------------------------------------------------------
__global__ __launch_bounds__(1024) void hmm_kernel(const float* __restrict__ Q,
                                                   const float* __restrict__ pi,
                                                   const float* __restrict__ ev,
                                                   float* __restrict__ ws) {
  int tid = threadIdx.x;
  int lane = tid & 63;
  int b = blockIdx.x * 16 + (tid >> 6);
  int i = lane >> 3, j = lane & 7;
  // Qlog[i][j] = Q[j][i] - LSE_c Q[j][c]  (reduce over i-group: xor 8,16,32)
  float q = Q[j * 8 + i];
  float m = q;
  m = fmaxf(m, __shfl_xor(m, 8, 64));
  m = fmaxf(m, __shfl_xor(m, 16, 64));
  m = fmaxf(m, __shfl_xor(m, 32, 64));
  float s = __expf(q - m);
  s += __shfl_xor(s, 8, 64); s += __shfl_xor(s, 16, 64); s += __shfl_xor(s, 32, 64);
  float qlog = q - (m + __logf(s));
  // log_pi[i]
  float p = pi[i];
  float mp = p;
  mp = fmaxf(mp, __shfl_xor(mp, 8, 64));
  mp = fmaxf(mp, __shfl_xor(mp, 16, 64));
  mp = fmaxf(mp, __shfl_xor(mp, 32, 64));
  float sp = __expf(p - mp);
  sp += __shfl_xor(sp, 8, 64); sp += __shfl_xor(sp, 16, 64); sp += __shfl_xor(sp, 32, 64);
  float lpi = p - (mp + __logf(sp));
  const float* evb = ev + (long)b * 4096;
  float v0 = evb[i] + lpi;
  float mv = v0;
  mv = fmaxf(mv, __shfl_xor(mv, 8, 64));
  mv = fmaxf(mv, __shfl_xor(mv, 16, 64));
  mv = fmaxf(mv, __shfl_xor(mv, 32, 64));
  float sv = __expf(v0 - mv);
  sv += __shfl_xor(sv, 8, 64); sv += __shfl_xor(sv, 16, 64); sv += __shfl_xor(sv, 32, 64);
  float lZ = mv + __logf(sv);
  float la = __shfl(v0, j * 9, 64) - lZ;
  float acc = lZ;
  float e = evb[8 + i];
  for (int t = 1; t < 512; ++t) {
    float e_next = (t < 511) ? evb[(t + 1) * 8 + i] : 0.f;
    // lp[i] = e + log sum_j exp(qlog[i][j] + la[j])   (vals in [-40,0]: no max needed)
    float sval = __expf(qlog + la);
    sval += __shfl_xor(sval, 1, 64);
    sval += __shfl_xor(sval, 2, 64);
    sval += __shfl_xor(sval, 4, 64);
    float lp = e + __logf(sval);
    float s2 = __expf(lp);
    s2 += __shfl_xor(s2, 8, 64);
    s2 += __shfl_xor(s2, 16, 64);
    s2 += __shfl_xor(s2, 32, 64);
    float lZt = __logf(s2);
    la = __shfl(lp, j * 9, 64) - lZt;
    acc += lZt;
    e = e_next;
  }
  if (lane == 0) atomicAdd(&ws[2], acc);
}

// ---------------------------------------------------------------------------
// decoder: x_hat = leaky(z@Wd1+bd1)@Wd2+bd2 ; recon accumulation
// block = 16 rows, 256 threads
// ---------------------------------------------------------------------------
__global__ __launch_bounds__(256) void dec_kernel(
    const float* __restrict__ x, const float* __restrict__ z,
    const float* __restrict__ Wd1, const float* __restrict__ bd1,
    const float* __restrict__ Wd2, const float* __restrict__ bd2,
    float* __restrict__ xhat, float* __restrict__ ws) {
  __shared__ __align__(16) float zT[16][20];
  __shared__ __align__(16) float h2T[256][20];
  __shared__ float sred;
  int tid = threadIdx.x;
  long row0 = (long)blockIdx.x * 16;
  if (tid == 0) sred = 0.f;
  {
    int r = tid >> 4, d = tid & 15;
    zT[d][r] = z[(row0 + r) * 16 + d];
  }
  __syncthreads();
  int tr = tid >> 6, tc = tid & 63;
  float acc[4][4];
  #pragma unroll
  for (int rr = 0; rr < 4; ++rr)
    #pragma unroll
    for (int cc = 0; cc < 4; ++cc) acc[rr][cc] = 0.f;
  #pragma unroll
  for (int d = 0; d < 16; ++d) {
    float4 av = *(const float4*)&zT[d][4 * tr];
    float4 bv = *(const float4*)&Wd1[d * 256 + 4 * tc];
    float am[4] = {av.x, av.y, av.z, av.w};
    float bm[4] = {bv.x, bv.y, bv.z, bv.w};
    #pragma unroll
    for (int rr = 0; rr < 4; ++rr)
      #pragma unroll
      for (int cc = 0; cc < 4; ++cc) acc[rr][cc] += am[rr] * bm[cc];
  }
  {
    float4 bv = *(const float4*)&bd1[4 * tc];
    float bm[4] = {bv.x, bv.y, bv.z, bv.w};
    #pragma unroll
    for (int rr = 0; rr < 4; ++rr)
      #pragma unroll
      for (int cc = 0; cc < 4; ++cc)
        h2T[4 * tc + cc][4 * tr + rr] = leakyf(acc[rr][cc] + bm[cc]);
  }
  __syncthreads();
  // phase B: rows 4*tr..4*tr+3, cols tc and tc+64
  float acc2[4][2];
  #pragma unroll
  for (int rr = 0; rr < 4; ++rr) { acc2[rr][0] = 0.f; acc2[rr][1] = 0.f; }
  #pragma unroll 2
  for (int i = 0; i < 256; ++i) {
    float4 av = *(const float4*)&h2T[i][4 * tr];
    float w0 = Wd2[i * 128 + tc];
    float w1_ = Wd2[i * 128 + tc + 64];
    float am[4] = {av.x, av.y, av.z, av.w};
    #pragma unroll
    for (int rr = 0; rr < 4; ++rr) {
      acc2[rr][0] += am[rr] * w0;
      acc2[rr][1] += am[rr] * w1_;
    }
  }
  float C0 = -0.5f * logf(6.2831853071795864f * VAR_F);
  float rsum = 0.f;
  #pragma unroll
  for (int rr = 0; rr < 4; ++rr) {
    long row = row0 + 4 * tr + rr;
    #pragma unroll
    for (int cc = 0; cc < 2; ++cc) {
      int col = tc + cc * 64;
      float xh = acc2[rr][cc] + bd2[col];
      xhat[row * 128 + col] = xh;
      float d_ = x[row * 128 + col] - xh;
      rsum += C0 - d_ * d_ * (0.5f / VAR_F);
    }
  }
  #pragma unroll
  for (int off = 1; off < 64; off <<= 1) rsum += __shfl_xor(rsum, off, 64);
  if ((tid & 63) == 0) atomicAdd(&sred, rsum);
  __syncthreads();
  if (tid == 0) atomicAdd(&ws[0], sred);
}

__global__ void fin_kernel(const float* __restrict__ ws, float* __restrict__ out) {
  float loss = -((ws[0] - ws[1] + ws[2]) * (1.f / 64.f));
  out[LOSS_OFF] = loss;
}

extern "C" void kernel_launch(void* const* d_in, const int* in_sizes, int n_in,
                              void* d_out, int out_size, void* d_ws, size_t ws_size,
                              hipStream_t stream) {
  (void)in_sizes; (void)n_in; (void)out_size; (void)ws_size;
  const float* x   = (const float*)d_in[0];
  const float* eps = (const float*)d_in[1];
  const float* W1  = (const float*)d_in[2];
  const float* b1  = (const float*)d_in[3];
  const float* W2  = (const float*)d_in[4];
  const float* b2  = (const float*)d_in[5];
  const float* Wt1 = (const float*)d_in[6];
  const float* bt1 = (const float*)d_in[7];
  const float* Wt2 = (const float*)d_in[8];
  const float* bt2 = (const float*)d_in[9];
  const float* Wd1 = (const float*)d_in[10];
  const float* bd1 = (const float*)d_in[11];
  const float* Wd2 = (const float*)d_in[12];
  const float* bd2 = (const float*)d_in[13];
  const float* Q   = (const float*)d_in[14];
  const float* pi  = (const float*)d_in[15];
  const float* im  = (const float*)d_in[16];
  const float* ic  = (const float*)d_in[17];
  const float* cv  = (const float*)d_in[18];
  float* out = (float*)d_out;
  float* ws  = (float*)d_ws;
  float* z_out = out + Z_OUT_OFF;
  float* ev = out;  // stage ev in x_hat region; consumed by hmm before dec overwrites

  hipMemsetAsync(ws, 0, 16, stream);
  prep_kernel<<<16, 256, 0, stream>>>(ic, cv, ws);
  enc_kernel<<<2048, 256, 0, stream>>>(x, eps, W1, b1, W2, b2, z_out, ws);
  ev0_kernel<<<2, 256, 0, stream>>>(z_out, im, ws, ev);
  evt_kernel<<<dim3(32, 8), 512, 0, stream>>>(z_out, Wt1, bt1, Wt2, bt2, ws, ev);
  hmm_kernel<<<4, 1024, 0, stream>>>(Q, pi, ev, ws);
  dec_kernel<<<2048, 256, 0, stream>>>(x, z_out, Wd1, bd1, Wd2, bd2, out, ws);
  fin_kernel<<<1, 1, 0, stream>>>(ws, out);
}

// Round 2
// 570.222 us; speedup vs baseline: 1.2563x; 1.2563x over previous
//
#include <hip/hip_runtime.h>
#include <math.h>

#define B_SZ   64
#define T_SZ   512
#define DOBS   128
#define DLAT   16
#define DHID   256
#define K_SZ   8
#define ROWS_T 32704   // B*(T-1)

#define LOG2PI_F 1.8378770664093453f
#define VAR_F    5.0e-4f

// ws float offsets
#define LINV0_OFF   16
#define LOGDET0_OFF 2064
#define LINVT_OFF   2080
#define LOGDETT_OFF 4128
// ws[0]=recon_sum ws[1]=logq_sum ws[2]=msm_sum

#define Z_OUT_OFF   4194304   // B*T*DOBS
#define LOSS_OFF    4718592   // + B*T*DLAT

__device__ __forceinline__ float leakyf(float v) { return v > 0.f ? v : 0.01f * v; }
__device__ __forceinline__ float dot4(float4 a, float4 b) {
  return a.x*b.x + a.y*b.y + a.z*b.z + a.w*b.w;
}
__device__ __forceinline__ void axpy4(float4& a, float s, float4 b) {
  a.x += s*b.x; a.y += s*b.y; a.z += s*b.z; a.w += s*b.w;
}

// ---------------------------------------------------------------------------
// prep: per-k Cholesky of C C^T + 1e-6 I, then Linv (lower-tri inverse), logdet.
// ---------------------------------------------------------------------------
__global__ __launch_bounds__(256) void prep_kernel(const float* __restrict__ init_cov,
                                                   const float* __restrict__ covs,
                                                   float* __restrict__ ws) {
  __shared__ float M[16][16];
  __shared__ float L[16][16];
  __shared__ float X[16][17];
  int job = blockIdx.x;
  const float* C = (job < 8) ? (init_cov + job * 256) : (covs + (job - 8) * 256);
  float* linv = ws + ((job < 8) ? (LINV0_OFF + job * 256) : (LINVT_OFF + (job - 8) * 256));
  float* logdet = ws + ((job < 8) ? (LOGDET0_OFF + job) : (LOGDETT_OFF + (job - 8)));
  int tid = threadIdx.x;
  int i = tid >> 4, j = tid & 15;
  {
    float s = (i == j) ? 1e-6f : 0.f;
    #pragma unroll
    for (int p = 0; p < 16; ++p) s += C[i * 16 + p] * C[j * 16 + p];
    M[i][j] = s;
  }
  __syncthreads();
  for (int c = 0; c < 16; ++c) {
    if (tid == 0) {
      float s = M[c][c];
      for (int p = 0; p < c; ++p) s -= L[c][p] * L[c][p];
      L[c][c] = sqrtf(s);
    }
    __syncthreads();
    if (tid > c && tid < 16) {
      float s = M[tid][c];
      for (int p = 0; p < c; ++p) s -= L[tid][p] * L[c][p];
      L[tid][c] = s / L[c][c];
    }
    __syncthreads();
  }
  if (tid < 16) {
    for (int r = 0; r < 16; ++r) {
      float s = (r == tid) ? 1.f : 0.f;
      for (int p = tid; p < r; ++p) s -= L[r][p] * X[p][tid];
      X[r][tid] = (r >= tid) ? s / L[r][r] : 0.f;
    }
  }
  __syncthreads();
  linv[i * 16 + j] = X[i][j];
  if (tid == 0) {
    float s = 0.f;
    for (int d = 0; d < 16; ++d) s += logf(L[d][d]);
    *logdet = 2.f * s;
  }
}

// ---------------------------------------------------------------------------
// encoder: h = leaky(x@W1+b1); enc = h@W2+b2; z = mu + exp(.5 lv)*eps; logq acc
// ---------------------------------------------------------------------------
__global__ __launch_bounds__(256) void enc_kernel(
    const float* __restrict__ x, const float* __restrict__ eps,
    const float* __restrict__ W1, const float* __restrict__ b1,
    const float* __restrict__ W2, const float* __restrict__ b2,
    float* __restrict__ z_out, float* __restrict__ ws) {
  __shared__ __align__(16) float xT[128][20];
  __shared__ __align__(16) float hs[16][260];
  __shared__ float sred;
  int tid = threadIdx.x;
  long row0 = (long)blockIdx.x * 16;
  if (tid == 0) sred = 0.f;
  const float* xblk = x + row0 * DOBS;
  #pragma unroll
  for (int q = 0; q < 8; ++q) {
    int e = tid + q * 256;
    xT[e & 127][e >> 7] = xblk[e];
  }
  __syncthreads();
  int tr = tid >> 6, tc = tid & 63;
  float acc[4][4];
  #pragma unroll
  for (int rr = 0; rr < 4; ++rr)
    #pragma unroll
    for (int cc = 0; cc < 4; ++cc) acc[rr][cc] = 0.f;
  #pragma unroll 4
  for (int d = 0; d < 128; ++d) {
    float4 av = *(const float4*)&xT[d][4 * tr];
    float4 bv = *(const float4*)&W1[d * 256 + 4 * tc];
    float am[4] = {av.x, av.y, av.z, av.w};
    float bm[4] = {bv.x, bv.y, bv.z, bv.w};
    #pragma unroll
    for (int rr = 0; rr < 4; ++rr)
      #pragma unroll
      for (int cc = 0; cc < 4; ++cc) acc[rr][cc] += am[rr] * bm[cc];
  }
  {
    float4 b1v = *(const float4*)&b1[4 * tc];
    float bm[4] = {b1v.x, b1v.y, b1v.z, b1v.w};
    #pragma unroll
    for (int rr = 0; rr < 4; ++rr)
      #pragma unroll
      for (int cc = 0; cc < 4; ++cc)
        hs[4 * tr + rr][4 * tc + cc] = leakyf(acc[rr][cc] + bm[cc]);
  }
  __syncthreads();
  int r = tid >> 4, c = tid & 15;
  float e0 = b2[c], e1 = b2[c + 16];
  const float* W2c = W2 + c;
  #pragma unroll 2
  for (int i4 = 0; i4 < 64; ++i4) {
    float4 h = *(const float4*)&hs[r][4 * i4];
    int ib = i4 * 128;
    e0 += h.x * W2c[ib];      e1 += h.x * W2c[ib + 16];
    e0 += h.y * W2c[ib + 32]; e1 += h.y * W2c[ib + 48];
    e0 += h.z * W2c[ib + 64]; e1 += h.z * W2c[ib + 80];
    e0 += h.w * W2c[ib + 96]; e1 += h.w * W2c[ib + 112];
  }
  long rowg = row0 + r;
  float epsv = eps[rowg * 16 + c];
  float zv = e0 + expf(0.5f * e1) * epsv;
  z_out[rowg * 16 + c] = zv;
  float zz = zv - e0;
  float contrib = e1 + zz * zz * expf(-e1);
  contrib += __shfl_xor(contrib, 1, 64);
  contrib += __shfl_xor(contrib, 2, 64);
  contrib += __shfl_xor(contrib, 4, 64);
  contrib += __shfl_xor(contrib, 8, 64);
  if (c == 0) atomicAdd(&sred, -0.5f * (16.f * LOG2PI_F + contrib));
  __syncthreads();
  if (tid == 0) atomicAdd(&ws[1], sred);
}

// ---------------------------------------------------------------------------
// ev0: ev[b,0,k] from init_mean / Linv0
// ---------------------------------------------------------------------------
__global__ __launch_bounds__(256) void ev0_kernel(const float* __restrict__ z,
                                                  const float* __restrict__ init_mean,
                                                  const float* __restrict__ ws,
                                                  float* __restrict__ ev) {
  int gid = blockIdx.x * 256 + threadIdx.x;
  if (gid >= B_SZ * K_SZ) return;
  int k = gid & 7, b = gid >> 3;
  const float* zr = z + (long)b * T_SZ * 16;
  const float* linv = ws + LINV0_OFF + k * 256;
  float diff[16];
  #pragma unroll
  for (int d = 0; d < 16; ++d) diff[d] = zr[d] - init_mean[k * 16 + d];
  float quad = 0.f;
  #pragma unroll
  for (int i2 = 0; i2 < 16; ++i2) {
    float s = 0.f;
    #pragma unroll
    for (int jj = 0; jj < 16; ++jj) s += linv[i2 * 16 + jj] * diff[jj];
    quad += s * s;
  }
  ev[(long)b * T_SZ * 8 + k] = -0.5f * (16.f * LOG2PI_F + ws[LOGDET0_OFF + k] + quad);
}

// ---------------------------------------------------------------------------
// evt: transition MLP + mvn logprob.
// grid (64, 8), 512 threads; ONE row per thread (512 rows/block).
// 2 blocks/CU (LDS 34KB), 16 waves/CU. Weights LDS-staged; all weight reads
// are wave-uniform broadcasts (conflict-free).
// ---------------------------------------------------------------------------
__global__ __launch_bounds__(512) void evt_kernel(
    const float* __restrict__ z, const float* __restrict__ Wt1,
    const float* __restrict__ bt1, const float* __restrict__ Wt2,
    const float* __restrict__ bt2, const float* __restrict__ ws,
    float* __restrict__ ev) {
  __shared__ __align__(16) float w1t[256][16];   // [i][d] = Wt1[k][d][i]
  __shared__ __align__(16) float w2s[256][16];   // [i][d2] = Wt2[k][i][d2]
  __shared__ float bt1s[256];
  __shared__ __align__(16) float linvs[256];
  int tid = threadIdx.x;
  int k = blockIdx.y;
  for (int e = tid; e < 4096; e += 512) w1t[e & 255][e >> 8] = Wt1[k * 4096 + e];
  for (int e = tid; e < 4096; e += 512) ((float*)w2s)[e] = Wt2[k * 4096 + e];
  if (tid < 256) bt1s[tid] = bt1[k * 256 + tid];
  else if (tid < 512) linvs[tid - 256] = ws[LINVT_OFF + k * 256 + (tid - 256)];
  float logdetk = ws[LOGDETT_OFF + k];
  __syncthreads();

  int r = blockIdx.x * 512 + tid;
  if (r >= ROWS_T) return;
  int b = r / 511, tp = r % 511;
  const float4* zr4 = (const float4*)(z + ((long)(b * 512 + tp)) * 16);
  float4 z0 = zr4[0], z1 = zr4[1], z2 = zr4[2], z3 = zr4[3];
  float4 m0 = make_float4(0.f, 0.f, 0.f, 0.f), m1 = m0, m2 = m0, m3 = m0;

  #pragma unroll 4
  for (int i = 0; i < 256; ++i) {
    const float4* wr = (const float4*)&w1t[i][0];
    float a01 = dot4(z0, wr[0]) + dot4(z1, wr[1]);
    float a23 = dot4(z2, wr[2]) + dot4(z3, wr[3]);
    float a = bt1s[i] + a01 + a23;
    // stable softplus with fast transcendentals
    float t = __expf(-fabsf(a));
    float s = fmaxf(a, 0.f) + __logf(1.f + t);
    const float4* vr = (const float4*)&w2s[i][0];
    axpy4(m0, s, vr[0]);
    axpy4(m1, s, vr[1]);
    axpy4(m2, s, vr[2]);
    axpy4(m3, s, vr[3]);
  }

  // diff = z[b, tp+1] - (mean + bt2)
  const float4* zc4 = (const float4*)(z + ((long)(b * 512 + tp + 1)) * 16);
  const float4* b2p = (const float4*)(bt2 + k * 16);
  float4 df[4];
  df[0] = zc4[0]; df[1] = zc4[1]; df[2] = zc4[2]; df[3] = zc4[3];
  float4 bb0 = b2p[0], bb1 = b2p[1], bb2 = b2p[2], bb3 = b2p[3];
  df[0].x -= m0.x + bb0.x; df[0].y -= m0.y + bb0.y; df[0].z -= m0.z + bb0.z; df[0].w -= m0.w + bb0.w;
  df[1].x -= m1.x + bb1.x; df[1].y -= m1.y + bb1.y; df[1].z -= m1.z + bb1.z; df[1].w -= m1.w + bb1.w;
  df[2].x -= m2.x + bb2.x; df[2].y -= m2.y + bb2.y; df[2].z -= m2.z + bb2.z; df[2].w -= m2.w + bb2.w;
  df[3].x -= m3.x + bb3.x; df[3].y -= m3.y + bb3.y; df[3].z -= m3.z + bb3.z; df[3].w -= m3.w + bb3.w;
  float quad = 0.f;
  #pragma unroll
  for (int i2 = 0; i2 < 16; ++i2) {
    const float4* lr = (const float4*)&linvs[i2 * 16];
    float s2 = dot4(lr[0], df[0]) + dot4(lr[1], df[1])
             + dot4(lr[2], df[2]) + dot4(lr[3], df[3]);
    quad += s2 * s2;
  }
  ev[((long)(b * 512 + tp + 1)) * 8 + k] = -0.5f * (16.f * LOG2PI_F + logdetk + quad);
}

// ---------------------------------------------------------------------------
// HMM forward: one wave per batch b; lane = (i,j) in 8x8. 4 blocks x 1024.
// ---------------------------------------------------------------------------
__global__ __launch_bounds__(1024) void hmm_kernel(const float* __restrict__ Q,
                                                   const float* __restrict__ pi,
                                                   const float* __restrict__ ev,
                                                   float* __restrict__ ws) {
  int tid = threadIdx.x;
  int lane = tid & 63;
  int b = blockIdx.x * 16 + (tid >> 6);
  int i = lane >> 3, j = lane & 7;
  float q = Q[j * 8 + i];
  float m = q;
  m = fmaxf(m, __shfl_xor(m, 8, 64));
  m = fmaxf(m, __shfl_xor(m, 16, 64));
  m = fmaxf(m, __shfl_xor(m, 32, 64));
  float s = __expf(q - m);
  s += __shfl_xor(s, 8, 64); s += __shfl_xor(s, 16, 64); s += __shfl_xor(s, 32, 64);
  float qlog = q - (m + __logf(s));
  float p = pi[i];
  float mp = p;
  mp = fmaxf(mp, __shfl_xor(mp, 8, 64));
  mp = fmaxf(mp, __shfl_xor(mp, 16, 64));
  mp = fmaxf(mp, __shfl_xor(mp, 32, 64));
  float sp = __expf(p - mp);
  sp += __shfl_xor(sp, 8, 64); sp += __shfl_xor(sp, 16, 64); sp += __shfl_xor(sp, 32, 64);
  float lpi = p - (mp + __logf(sp));
  const float* evb = ev + (long)b * 4096;
  float v0 = evb[i] + lpi;
  float mv = v0;
  mv = fmaxf(mv, __shfl_xor(mv, 8, 64));
  mv = fmaxf(mv, __shfl_xor(mv, 16, 64));
  mv = fmaxf(mv, __shfl_xor(mv, 32, 64));
  float sv = __expf(v0 - mv);
  sv += __shfl_xor(sv, 8, 64); sv += __shfl_xor(sv, 16, 64); sv += __shfl_xor(sv, 32, 64);
  float lZ = mv + __logf(sv);
  float la = __shfl(v0, j * 9, 64) - lZ;
  float acc = lZ;
  float e = evb[8 + i];
  for (int t = 1; t < 512; ++t) {
    float e_next = (t < 511) ? evb[(t + 1) * 8 + i] : 0.f;
    float sval = __expf(qlog + la);
    sval += __shfl_xor(sval, 1, 64);
    sval += __shfl_xor(sval, 2, 64);
    sval += __shfl_xor(sval, 4, 64);
    float lp = e + __logf(sval);
    float s2 = __expf(lp);
    s2 += __shfl_xor(s2, 8, 64);
    s2 += __shfl_xor(s2, 16, 64);
    s2 += __shfl_xor(s2, 32, 64);
    float lZt = __logf(s2);
    la = __shfl(lp, j * 9, 64) - lZt;
    acc += lZt;
    e = e_next;
  }
  if (lane == 0) atomicAdd(&ws[2], acc);
}

// ---------------------------------------------------------------------------
// decoder: x_hat = leaky(z@Wd1+bd1)@Wd2+bd2 ; recon accumulation
// ---------------------------------------------------------------------------
__global__ __launch_bounds__(256) void dec_kernel(
    const float* __restrict__ x, const float* __restrict__ z,
    const float* __restrict__ Wd1, const float* __restrict__ bd1,
    const float* __restrict__ Wd2, const float* __restrict__ bd2,
    float* __restrict__ xhat, float* __restrict__ ws) {
  __shared__ __align__(16) float zT[16][20];
  __shared__ __align__(16) float h2T[256][20];
  __shared__ float sred;
  int tid = threadIdx.x;
  long row0 = (long)blockIdx.x * 16;
  if (tid == 0) sred = 0.f;
  {
    int r = tid >> 4, d = tid & 15;
    zT[d][r] = z[(row0 + r) * 16 + d];
  }
  __syncthreads();
  int tr = tid >> 6, tc = tid & 63;
  float acc[4][4];
  #pragma unroll
  for (int rr = 0; rr < 4; ++rr)
    #pragma unroll
    for (int cc = 0; cc < 4; ++cc) acc[rr][cc] = 0.f;
  #pragma unroll
  for (int d = 0; d < 16; ++d) {
    float4 av = *(const float4*)&zT[d][4 * tr];
    float4 bv = *(const float4*)&Wd1[d * 256 + 4 * tc];
    float am[4] = {av.x, av.y, av.z, av.w};
    float bm[4] = {bv.x, bv.y, bv.z, bv.w};
    #pragma unroll
    for (int rr = 0; rr < 4; ++rr)
      #pragma unroll
      for (int cc = 0; cc < 4; ++cc) acc[rr][cc] += am[rr] * bm[cc];
  }
  {
    float4 bv = *(const float4*)&bd1[4 * tc];
    float bm[4] = {bv.x, bv.y, bv.z, bv.w};
    #pragma unroll
    for (int rr = 0; rr < 4; ++rr)
      #pragma unroll
      for (int cc = 0; cc < 4; ++cc)
        h2T[4 * tc + cc][4 * tr + rr] = leakyf(acc[rr][cc] + bm[cc]);
  }
  __syncthreads();
  float acc2[4][2];
  #pragma unroll
  for (int rr = 0; rr < 4; ++rr) { acc2[rr][0] = 0.f; acc2[rr][1] = 0.f; }
  #pragma unroll 2
  for (int i = 0; i < 256; ++i) {
    float4 av = *(const float4*)&h2T[i][4 * tr];
    float w0 = Wd2[i * 128 + tc];
    float w1_ = Wd2[i * 128 + tc + 64];
    float am[4] = {av.x, av.y, av.z, av.w};
    #pragma unroll
    for (int rr = 0; rr < 4; ++rr) {
      acc2[rr][0] += am[rr] * w0;
      acc2[rr][1] += am[rr] * w1_;
    }
  }
  float C0 = -0.5f * logf(6.2831853071795864f * VAR_F);
  float rsum = 0.f;
  #pragma unroll
  for (int rr = 0; rr < 4; ++rr) {
    long row = row0 + 4 * tr + rr;
    #pragma unroll
    for (int cc = 0; cc < 2; ++cc) {
      int col = tc + cc * 64;
      float xh = acc2[rr][cc] + bd2[col];
      xhat[row * 128 + col] = xh;
      float d_ = x[row * 128 + col] - xh;
      rsum += C0 - d_ * d_ * (0.5f / VAR_F);
    }
  }
  #pragma unroll
  for (int off = 1; off < 64; off <<= 1) rsum += __shfl_xor(rsum, off, 64);
  if ((tid & 63) == 0) atomicAdd(&sred, rsum);
  __syncthreads();
  if (tid == 0) atomicAdd(&ws[0], sred);
}

__global__ void fin_kernel(const float* __restrict__ ws, float* __restrict__ out) {
  float loss = -((ws[0] - ws[1] + ws[2]) * (1.f / 64.f));
  out[LOSS_OFF] = loss;
}

extern "C" void kernel_launch(void* const* d_in, const int* in_sizes, int n_in,
                              void* d_out, int out_size, void* d_ws, size_t ws_size,
                              hipStream_t stream) {
  (void)in_sizes; (void)n_in; (void)out_size; (void)ws_size;
  const float* x   = (const float*)d_in[0];
  const float* eps = (const float*)d_in[1];
  const float* W1  = (const float*)d_in[2];
  const float* b1  = (const float*)d_in[3];
  const float* W2  = (const float*)d_in[4];
  const float* b2  = (const float*)d_in[5];
  const float* Wt1 = (const float*)d_in[6];
  const float* bt1 = (const float*)d_in[7];
  const float* Wt2 = (const float*)d_in[8];
  const float* bt2 = (const float*)d_in[9];
  const float* Wd1 = (const float*)d_in[10];
  const float* bd1 = (const float*)d_in[11];
  const float* Wd2 = (const float*)d_in[12];
  const float* bd2 = (const float*)d_in[13];
  const float* Q   = (const float*)d_in[14];
  const float* pi  = (const float*)d_in[15];
  const float* im  = (const float*)d_in[16];
  const float* ic  = (const float*)d_in[17];
  const float* cv  = (const float*)d_in[18];
  float* out = (float*)d_out;
  float* ws  = (float*)d_ws;
  float* z_out = out + Z_OUT_OFF;
  float* ev = out;  // stage ev in x_hat region; consumed by hmm before dec overwrites

  hipMemsetAsync(ws, 0, 16, stream);
  prep_kernel<<<16, 256, 0, stream>>>(ic, cv, ws);
  enc_kernel<<<2048, 256, 0, stream>>>(x, eps, W1, b1, W2, b2, z_out, ws);
  ev0_kernel<<<2, 256, 0, stream>>>(z_out, im, ws, ev);
  evt_kernel<<<dim3(64, 8), 512, 0, stream>>>(z_out, Wt1, bt1, Wt2, bt2, ws, ev);
  hmm_kernel<<<4, 1024, 0, stream>>>(Q, pi, ev, ws);
  dec_kernel<<<2048, 256, 0, stream>>>(x, z_out, Wd1, bd1, Wd2, bd2, out, ws);
  fin_kernel<<<1, 1, 0, stream>>>(ws, out);
}

// Round 3
// 512.868 us; speedup vs baseline: 1.3967x; 1.1118x over previous
//
#include <hip/hip_runtime.h>
#include <math.h>

#define B_SZ   64
#define T_SZ   512
#define DOBS   128
#define DLAT   16
#define DHID   256
#define K_SZ   8
#define ROWS_T 32704   // B*(T-1)

#define LOG2PI_F 1.8378770664093453f
#define VAR_F    5.0e-4f

// ws float offsets
#define LINV0_OFF   16
#define LOGDET0_OFF 2064
#define LINVT_OFF   2080
#define LOGDETT_OFF 4128
// ws[0]=recon_sum ws[1]=logq_sum ws[2]=msm_sum

#define Z_OUT_OFF   4194304   // B*T*DOBS
#define LOSS_OFF    4718592   // + B*T*DLAT

__device__ __forceinline__ float leakyf(float v) { return v > 0.f ? v : 0.01f * v; }
__device__ __forceinline__ float dot4(float4 a, float4 b) {
  return a.x*b.x + a.y*b.y + a.z*b.z + a.w*b.w;
}
__device__ __forceinline__ void axpy4(float4& a, float s, float4 b) {
  a.x += s*b.x; a.y += s*b.y; a.z += s*b.z; a.w += s*b.w;
}

// ---------------------------------------------------------------------------
// prep: per-k Cholesky of C C^T + 1e-6 I, then Linv (lower-tri inverse), logdet.
// ---------------------------------------------------------------------------
__global__ __launch_bounds__(256) void prep_kernel(const float* __restrict__ init_cov,
                                                   const float* __restrict__ covs,
                                                   float* __restrict__ ws) {
  __shared__ float M[16][16];
  __shared__ float L[16][16];
  __shared__ float X[16][17];
  int job = blockIdx.x;
  const float* C = (job < 8) ? (init_cov + job * 256) : (covs + (job - 8) * 256);
  float* linv = ws + ((job < 8) ? (LINV0_OFF + job * 256) : (LINVT_OFF + (job - 8) * 256));
  float* logdet = ws + ((job < 8) ? (LOGDET0_OFF + job) : (LOGDETT_OFF + (job - 8)));
  int tid = threadIdx.x;
  int i = tid >> 4, j = tid & 15;
  {
    float s = (i == j) ? 1e-6f : 0.f;
    #pragma unroll
    for (int p = 0; p < 16; ++p) s += C[i * 16 + p] * C[j * 16 + p];
    M[i][j] = s;
  }
  __syncthreads();
  for (int c = 0; c < 16; ++c) {
    if (tid == 0) {
      float s = M[c][c];
      for (int p = 0; p < c; ++p) s -= L[c][p] * L[c][p];
      L[c][c] = sqrtf(s);
    }
    __syncthreads();
    if (tid > c && tid < 16) {
      float s = M[tid][c];
      for (int p = 0; p < c; ++p) s -= L[tid][p] * L[c][p];
      L[tid][c] = s / L[c][c];
    }
    __syncthreads();
  }
  if (tid < 16) {
    for (int r = 0; r < 16; ++r) {
      float s = (r == tid) ? 1.f : 0.f;
      for (int p = tid; p < r; ++p) s -= L[r][p] * X[p][tid];
      X[r][tid] = (r >= tid) ? s / L[r][r] : 0.f;
    }
  }
  __syncthreads();
  linv[i * 16 + j] = X[i][j];
  if (tid == 0) {
    float s = 0.f;
    for (int d = 0; d < 16; ++d) s += logf(L[d][d]);
    *logdet = 2.f * s;
  }
}

// ---------------------------------------------------------------------------
// encoder: h = leaky(x@W1+b1); enc = h@W2+b2; z = mu + exp(.5 lv)*eps; logq acc
// ---------------------------------------------------------------------------
__global__ __launch_bounds__(256) void enc_kernel(
    const float* __restrict__ x, const float* __restrict__ eps,
    const float* __restrict__ W1, const float* __restrict__ b1,
    const float* __restrict__ W2, const float* __restrict__ b2,
    float* __restrict__ z_out, float* __restrict__ ws) {
  __shared__ __align__(16) float xT[128][20];
  __shared__ __align__(16) float hs[16][260];
  __shared__ float sred;
  int tid = threadIdx.x;
  long row0 = (long)blockIdx.x * 16;
  if (tid == 0) sred = 0.f;
  const float* xblk = x + row0 * DOBS;
  #pragma unroll
  for (int q = 0; q < 8; ++q) {
    int e = tid + q * 256;
    xT[e & 127][e >> 7] = xblk[e];
  }
  __syncthreads();
  int tr = tid >> 6, tc = tid & 63;
  float acc[4][4];
  #pragma unroll
  for (int rr = 0; rr < 4; ++rr)
    #pragma unroll
    for (int cc = 0; cc < 4; ++cc) acc[rr][cc] = 0.f;
  #pragma unroll 4
  for (int d = 0; d < 128; ++d) {
    float4 av = *(const float4*)&xT[d][4 * tr];
    float4 bv = *(const float4*)&W1[d * 256 + 4 * tc];
    float am[4] = {av.x, av.y, av.z, av.w};
    float bm[4] = {bv.x, bv.y, bv.z, bv.w};
    #pragma unroll
    for (int rr = 0; rr < 4; ++rr)
      #pragma unroll
      for (int cc = 0; cc < 4; ++cc) acc[rr][cc] += am[rr] * bm[cc];
  }
  {
    float4 b1v = *(const float4*)&b1[4 * tc];
    float bm[4] = {b1v.x, b1v.y, b1v.z, b1v.w};
    #pragma unroll
    for (int rr = 0; rr < 4; ++rr)
      #pragma unroll
      for (int cc = 0; cc < 4; ++cc)
        hs[4 * tr + rr][4 * tc + cc] = leakyf(acc[rr][cc] + bm[cc]);
  }
  __syncthreads();
  int r = tid >> 4, c = tid & 15;
  float e0 = b2[c], e1 = b2[c + 16];
  const float* W2c = W2 + c;
  #pragma unroll 2
  for (int i4 = 0; i4 < 64; ++i4) {
    float4 h = *(const float4*)&hs[r][4 * i4];
    int ib = i4 * 128;
    e0 += h.x * W2c[ib];      e1 += h.x * W2c[ib + 16];
    e0 += h.y * W2c[ib + 32]; e1 += h.y * W2c[ib + 48];
    e0 += h.z * W2c[ib + 64]; e1 += h.z * W2c[ib + 80];
    e0 += h.w * W2c[ib + 96]; e1 += h.w * W2c[ib + 112];
  }
  long rowg = row0 + r;
  float epsv = eps[rowg * 16 + c];
  float zv = e0 + expf(0.5f * e1) * epsv;
  z_out[rowg * 16 + c] = zv;
  float zz = zv - e0;
  float contrib = e1 + zz * zz * expf(-e1);
  contrib += __shfl_xor(contrib, 1, 64);
  contrib += __shfl_xor(contrib, 2, 64);
  contrib += __shfl_xor(contrib, 4, 64);
  contrib += __shfl_xor(contrib, 8, 64);
  if (c == 0) atomicAdd(&sred, -0.5f * (16.f * LOG2PI_F + contrib));
  __syncthreads();
  if (tid == 0) atomicAdd(&ws[1], sred);
}

// ---------------------------------------------------------------------------
// ev0: ev[b,0,k] from init_mean / Linv0
// ---------------------------------------------------------------------------
__global__ __launch_bounds__(256) void ev0_kernel(const float* __restrict__ z,
                                                  const float* __restrict__ init_mean,
                                                  const float* __restrict__ ws,
                                                  float* __restrict__ ev) {
  int gid = blockIdx.x * 256 + threadIdx.x;
  if (gid >= B_SZ * K_SZ) return;
  int k = gid & 7, b = gid >> 3;
  const float* zr = z + (long)b * T_SZ * 16;
  const float* linv = ws + LINV0_OFF + k * 256;
  float diff[16];
  #pragma unroll
  for (int d = 0; d < 16; ++d) diff[d] = zr[d] - init_mean[k * 16 + d];
  float quad = 0.f;
  #pragma unroll
  for (int i2 = 0; i2 < 16; ++i2) {
    float s = 0.f;
    #pragma unroll
    for (int jj = 0; jj < 16; ++jj) s += linv[i2 * 16 + jj] * diff[jj];
    quad += s * s;
  }
  ev[(long)b * T_SZ * 8 + k] = -0.5f * (16.f * LOG2PI_F + ws[LOGDET0_OFF + k] + quad);
}

// ---------------------------------------------------------------------------
// evt: transition MLP + mvn logprob. grid (64,8), 512 thr, 1 row/thread.
// ---------------------------------------------------------------------------
__global__ __launch_bounds__(512) void evt_kernel(
    const float* __restrict__ z, const float* __restrict__ Wt1,
    const float* __restrict__ bt1, const float* __restrict__ Wt2,
    const float* __restrict__ bt2, const float* __restrict__ ws,
    float* __restrict__ ev) {
  __shared__ __align__(16) float w1t[256][16];   // [i][d] = Wt1[k][d][i]
  __shared__ __align__(16) float w2s[256][16];   // [i][d2] = Wt2[k][i][d2]
  __shared__ float bt1s[256];
  __shared__ __align__(16) float linvs[256];
  int tid = threadIdx.x;
  int k = blockIdx.y;
  for (int e = tid; e < 4096; e += 512) w1t[e & 255][e >> 8] = Wt1[k * 4096 + e];
  for (int e = tid; e < 4096; e += 512) ((float*)w2s)[e] = Wt2[k * 4096 + e];
  if (tid < 256) bt1s[tid] = bt1[k * 256 + tid];
  else if (tid < 512) linvs[tid - 256] = ws[LINVT_OFF + k * 256 + (tid - 256)];
  float logdetk = ws[LOGDETT_OFF + k];
  __syncthreads();

  int r = blockIdx.x * 512 + tid;
  if (r >= ROWS_T) return;
  int b = r / 511, tp = r % 511;
  const float4* zr4 = (const float4*)(z + ((long)(b * 512 + tp)) * 16);
  float4 z0 = zr4[0], z1 = zr4[1], z2 = zr4[2], z3 = zr4[3];
  float4 m0 = make_float4(0.f, 0.f, 0.f, 0.f), m1 = m0, m2 = m0, m3 = m0;

  #pragma unroll 4
  for (int i = 0; i < 256; ++i) {
    const float4* wr = (const float4*)&w1t[i][0];
    float a01 = dot4(z0, wr[0]) + dot4(z1, wr[1]);
    float a23 = dot4(z2, wr[2]) + dot4(z3, wr[3]);
    float a = bt1s[i] + a01 + a23;
    float t = __expf(-fabsf(a));
    float s = fmaxf(a, 0.f) + __logf(1.f + t);
    const float4* vr = (const float4*)&w2s[i][0];
    axpy4(m0, s, vr[0]);
    axpy4(m1, s, vr[1]);
    axpy4(m2, s, vr[2]);
    axpy4(m3, s, vr[3]);
  }

  const float4* zc4 = (const float4*)(z + ((long)(b * 512 + tp + 1)) * 16);
  const float4* b2p = (const float4*)(bt2 + k * 16);
  float4 df[4];
  df[0] = zc4[0]; df[1] = zc4[1]; df[2] = zc4[2]; df[3] = zc4[3];
  float4 bb0 = b2p[0], bb1 = b2p[1], bb2 = b2p[2], bb3 = b2p[3];
  df[0].x -= m0.x + bb0.x; df[0].y -= m0.y + bb0.y; df[0].z -= m0.z + bb0.z; df[0].w -= m0.w + bb0.w;
  df[1].x -= m1.x + bb1.x; df[1].y -= m1.y + bb1.y; df[1].z -= m1.z + bb1.z; df[1].w -= m1.w + bb1.w;
  df[2].x -= m2.x + bb2.x; df[2].y -= m2.y + bb2.y; df[2].z -= m2.z + bb2.z; df[2].w -= m2.w + bb2.w;
  df[3].x -= m3.x + bb3.x; df[3].y -= m3.y + bb3.y; df[3].z -= m3.z + bb3.z; df[3].w -= m3.w + bb3.w;
  float quad = 0.f;
  #pragma unroll
  for (int i2 = 0; i2 < 16; ++i2) {
    const float4* lr = (const float4*)&linvs[i2 * 16];
    float s2 = dot4(lr[0], df[0]) + dot4(lr[1], df[1])
             + dot4(lr[2], df[2]) + dot4(lr[3], df[3]);
    quad += s2 * s2;
  }
  ev[((long)(b * 512 + tp + 1)) * 8 + k] = -0.5f * (16.f * LOG2PI_F + logdetk + quad);
}

// ---------------------------------------------------------------------------
// HMM forward, scaled LINEAR-space: u <- f_t o (Qexp u), f_t = exp(ev_t - m_t)
// precomputed one step ahead (off the dependency chain). logZ = acc + log(sum u).
// 8 lanes per batch (lane=state), 8 batches/wave. grid 8 x 64.
// ---------------------------------------------------------------------------
__global__ __launch_bounds__(64) void hmm_kernel(const float* __restrict__ Q,
                                                 const float* __restrict__ pi,
                                                 const float* __restrict__ ev,
                                                 float* __restrict__ ws) {
  int lane = threadIdx.x & 63;
  int g = lane >> 3, i = lane & 7;
  int b = blockIdx.x * 8 + g;

  // Qexp row i in shuffle order: q[d] = Qexp[i][(i+d)&7], Qexp[i][j]=softmax(Q[j,:])[i]
  float q[8];
  #pragma unroll
  for (int d = 0; d < 8; ++d) {
    int j = (i + d) & 7;
    float mr = Q[j * 8 + 0];
    #pragma unroll
    for (int c = 1; c < 8; ++c) mr = fmaxf(mr, Q[j * 8 + c]);
    float rs = 0.f;
    #pragma unroll
    for (int c = 0; c < 8; ++c) rs += __expf(Q[j * 8 + c] - mr);
    q[d] = __expf(Q[j * 8 + i] - mr) / rs;
  }
  // log_pi[i]
  float mp = pi[0];
  #pragma unroll
  for (int c = 1; c < 8; ++c) mp = fmaxf(mp, pi[c]);
  float sp = 0.f;
  #pragma unroll
  for (int c = 0; c < 8; ++c) sp += __expf(pi[c] - mp);
  float lpi = pi[i] - mp - __logf(sp);

  const float* evb = ev + (long)b * 4096;
  // t=0 init (unnormalized)
  float lp0 = evb[i] + lpi;
  float m0 = lp0;
  m0 = fmaxf(m0, __shfl_xor(m0, 1, 64));
  m0 = fmaxf(m0, __shfl_xor(m0, 2, 64));
  m0 = fmaxf(m0, __shfl_xor(m0, 4, 64));
  float u = __expf(lp0 - m0);
  double acc = (double)m0;

  // shuffle source lanes (loop-invariant)
  int base = lane & 56;
  int x1 = base | ((i + 1) & 7), x2 = base | ((i + 2) & 7), x3 = base | ((i + 3) & 7);
  int x4 = base | ((i + 4) & 7), x5 = base | ((i + 5) & 7), x6 = base | ((i + 6) & 7);
  int x7 = base | ((i + 7) & 7);

  // prefetch factor for t=1
  float e1 = evb[8 + i];
  float mt = e1;
  mt = fmaxf(mt, __shfl_xor(mt, 1, 64));
  mt = fmaxf(mt, __shfl_xor(mt, 2, 64));
  mt = fmaxf(mt, __shfl_xor(mt, 4, 64));
  float f_nx = __expf(e1 - mt);
  float mt_nx = mt;

  for (int t = 1; t < 512; ++t) {
    float f = f_nx;
    float mtc = mt_nx;
    if (t < 511) {  // factor for t+1: independent of the chain, overlaps it
      float e = evb[(t + 1) * 8 + i];
      float m2 = e;
      m2 = fmaxf(m2, __shfl_xor(m2, 1, 64));
      m2 = fmaxf(m2, __shfl_xor(m2, 2, 64));
      m2 = fmaxf(m2, __shfl_xor(m2, 4, 64));
      f_nx = __expf(e - m2);
      mt_nx = m2;
    }
    float a1 = __shfl(u, x1, 64), a2 = __shfl(u, x2, 64), a3 = __shfl(u, x3, 64);
    float a4 = __shfl(u, x4, 64), a5 = __shfl(u, x5, 64), a6 = __shfl(u, x6, 64);
    float a7 = __shfl(u, x7, 64);
    float s = ((q[0] * u + q[1] * a1) + (q[2] * a2 + q[3] * a3))
            + ((q[4] * a4 + q[5] * a5) + (q[6] * a6 + q[7] * a7));
    u = f * s;
    acc += (double)mtc;
    if ((t & 15) == 0) {  // renormalize (amortized off the hot path)
      float rs = u;
      rs += __shfl_xor(rs, 1, 64);
      rs += __shfl_xor(rs, 2, 64);
      rs += __shfl_xor(rs, 4, 64);
      acc += (double)__logf(rs);
      u = u / rs;
    }
  }
  float rs = u;
  rs += __shfl_xor(rs, 1, 64);
  rs += __shfl_xor(rs, 2, 64);
  rs += __shfl_xor(rs, 4, 64);
  float logZ = (float)(acc + (double)__logf(rs));
  if (i == 0) atomicAdd(&ws[2], logZ);
}

// ---------------------------------------------------------------------------
// decoder: x_hat = leaky(z@Wd1+bd1)@Wd2+bd2 ; recon accumulation
// ---------------------------------------------------------------------------
__global__ __launch_bounds__(256) void dec_kernel(
    const float* __restrict__ x, const float* __restrict__ z,
    const float* __restrict__ Wd1, const float* __restrict__ bd1,
    const float* __restrict__ Wd2, const float* __restrict__ bd2,
    float* __restrict__ xhat, float* __restrict__ ws) {
  __shared__ __align__(16) float zT[16][20];
  __shared__ __align__(16) float h2T[256][20];
  __shared__ float sred;
  int tid = threadIdx.x;
  long row0 = (long)blockIdx.x * 16;
  if (tid == 0) sred = 0.f;
  {
    int r = tid >> 4, d = tid & 15;
    zT[d][r] = z[(row0 + r) * 16 + d];
  }
  __syncthreads();
  int tr = tid >> 6, tc = tid & 63;
  float acc[4][4];
  #pragma unroll
  for (int rr = 0; rr < 4; ++rr)
    #pragma unroll
    for (int cc = 0; cc < 4; ++cc) acc[rr][cc] = 0.f;
  #pragma unroll
  for (int d = 0; d < 16; ++d) {
    float4 av = *(const float4*)&zT[d][4 * tr];
    float4 bv = *(const float4*)&Wd1[d * 256 + 4 * tc];
    float am[4] = {av.x, av.y, av.z, av.w};
    float bm[4] = {bv.x, bv.y, bv.z, bv.w};
    #pragma unroll
    for (int rr = 0; rr < 4; ++rr)
      #pragma unroll
      for (int cc = 0; cc < 4; ++cc) acc[rr][cc] += am[rr] * bm[cc];
  }
  {
    float4 bv = *(const float4*)&bd1[4 * tc];
    float bm[4] = {bv.x, bv.y, bv.z, bv.w};
    #pragma unroll
    for (int rr = 0; rr < 4; ++rr)
      #pragma unroll
      for (int cc = 0; cc < 4; ++cc)
        h2T[4 * tc + cc][4 * tr + rr] = leakyf(acc[rr][cc] + bm[cc]);
  }
  __syncthreads();
  float acc2[4][2];
  #pragma unroll
  for (int rr = 0; rr < 4; ++rr) { acc2[rr][0] = 0.f; acc2[rr][1] = 0.f; }
  #pragma unroll 2
  for (int i = 0; i < 256; ++i) {
    float4 av = *(const float4*)&h2T[i][4 * tr];
    float w0 = Wd2[i * 128 + tc];
    float w1_ = Wd2[i * 128 + tc + 64];
    float am[4] = {av.x, av.y, av.z, av.w};
    #pragma unroll
    for (int rr = 0; rr < 4; ++rr) {
      acc2[rr][0] += am[rr] * w0;
      acc2[rr][1] += am[rr] * w1_;
    }
  }
  float C0 = -0.5f * logf(6.2831853071795864f * VAR_F);
  float rsum = 0.f;
  #pragma unroll
  for (int rr = 0; rr < 4; ++rr) {
    long row = row0 + 4 * tr + rr;
    #pragma unroll
    for (int cc = 0; cc < 2; ++cc) {
      int col = tc + cc * 64;
      float xh = acc2[rr][cc] + bd2[col];
      xhat[row * 128 + col] = xh;
      float d_ = x[row * 128 + col] - xh;
      rsum += C0 - d_ * d_ * (0.5f / VAR_F);
    }
  }
  #pragma unroll
  for (int off = 1; off < 64; off <<= 1) rsum += __shfl_xor(rsum, off, 64);
  if ((tid & 63) == 0) atomicAdd(&sred, rsum);
  __syncthreads();
  if (tid == 0) atomicAdd(&ws[0], sred);
}

__global__ void fin_kernel(const float* __restrict__ ws, float* __restrict__ out) {
  float loss = -((ws[0] - ws[1] + ws[2]) * (1.f / 64.f));
  out[LOSS_OFF] = loss;
}

extern "C" void kernel_launch(void* const* d_in, const int* in_sizes, int n_in,
                              void* d_out, int out_size, void* d_ws, size_t ws_size,
                              hipStream_t stream) {
  (void)in_sizes; (void)n_in; (void)out_size; (void)ws_size;
  const float* x   = (const float*)d_in[0];
  const float* eps = (const float*)d_in[1];
  const float* W1  = (const float*)d_in[2];
  const float* b1  = (const float*)d_in[3];
  const float* W2  = (const float*)d_in[4];
  const float* b2  = (const float*)d_in[5];
  const float* Wt1 = (const float*)d_in[6];
  const float* bt1 = (const float*)d_in[7];
  const float* Wt2 = (const float*)d_in[8];
  const float* bt2 = (const float*)d_in[9];
  const float* Wd1 = (const float*)d_in[10];
  const float* bd1 = (const float*)d_in[11];
  const float* Wd2 = (const float*)d_in[12];
  const float* bd2 = (const float*)d_in[13];
  const float* Q   = (const float*)d_in[14];
  const float* pi  = (const float*)d_in[15];
  const float* im  = (const float*)d_in[16];
  const float* ic  = (const float*)d_in[17];
  const float* cv  = (const float*)d_in[18];
  float* out = (float*)d_out;
  float* ws  = (float*)d_ws;
  float* z_out = out + Z_OUT_OFF;
  float* ev = out;  // stage ev in x_hat region; consumed by hmm before dec overwrites

  hipMemsetAsync(ws, 0, 16, stream);
  prep_kernel<<<16, 256, 0, stream>>>(ic, cv, ws);
  enc_kernel<<<2048, 256, 0, stream>>>(x, eps, W1, b1, W2, b2, z_out, ws);
  ev0_kernel<<<2, 256, 0, stream>>>(z_out, im, ws, ev);
  evt_kernel<<<dim3(64, 8), 512, 0, stream>>>(z_out, Wt1, bt1, Wt2, bt2, ws, ev);
  hmm_kernel<<<8, 64, 0, stream>>>(Q, pi, ev, ws);
  dec_kernel<<<2048, 256, 0, stream>>>(x, z_out, Wd1, bd1, Wd2, bd2, out, ws);
  fin_kernel<<<1, 1, 0, stream>>>(ws, out);
}

// Round 4
// 461.315 us; speedup vs baseline: 1.5528x; 1.1118x over previous
//
#include <hip/hip_runtime.h>
#include <math.h>

#define B_SZ   64
#define T_SZ   512
#define DOBS   128
#define DLAT   16
#define DHID   256
#define K_SZ   8
#define ROWS_T 32704   // B*(T-1)
#define ROWS_A 32768   // B*T (evt computes all, last row per batch discarded)

#define LOG2PI_F 1.8378770664093453f
#define VAR_F    5.0e-4f

// ws float offsets
#define LINV0_OFF   16
#define LOGDET0_OFF 2064
#define LINVT_OFF   2080
#define LOGDETT_OFF 4128
// ws[0]=recon_sum ws[1]=logq_sum ws[2]=msm_sum

#define Z_OUT_OFF   4194304   // B*T*DOBS
#define LOSS_OFF    4718592   // + B*T*DLAT

typedef __attribute__((ext_vector_type(8))) short short8;
typedef __attribute__((ext_vector_type(4))) float floatx4;

__device__ __forceinline__ float leakyf(float v) { return v > 0.f ? v : 0.01f * v; }
__device__ __forceinline__ float dot4(float4 a, float4 b) {
  return a.x*b.x + a.y*b.y + a.z*b.z + a.w*b.w;
}
__device__ __forceinline__ unsigned short f2bf(float f) {
  union { float f; unsigned int u; } v; v.f = f;
  unsigned int lsb = (v.u >> 16) & 1;
  v.u += 0x7fffu + lsb;   // round-to-nearest-even
  return (unsigned short)(v.u >> 16);
}

// ---------------------------------------------------------------------------
// prep: per-k Cholesky of C C^T + 1e-6 I, then Linv (lower-tri inverse), logdet.
// ---------------------------------------------------------------------------
__global__ __launch_bounds__(256) void prep_kernel(const float* __restrict__ init_cov,
                                                   const float* __restrict__ covs,
                                                   float* __restrict__ ws) {
  __shared__ float M[16][16];
  __shared__ float L[16][16];
  __shared__ float X[16][17];
  int job = blockIdx.x;
  const float* C = (job < 8) ? (init_cov + job * 256) : (covs + (job - 8) * 256);
  float* linv = ws + ((job < 8) ? (LINV0_OFF + job * 256) : (LINVT_OFF + (job - 8) * 256));
  float* logdet = ws + ((job < 8) ? (LOGDET0_OFF + job) : (LOGDETT_OFF + (job - 8)));
  int tid = threadIdx.x;
  int i = tid >> 4, j = tid & 15;
  {
    float s = (i == j) ? 1e-6f : 0.f;
    #pragma unroll
    for (int p = 0; p < 16; ++p) s += C[i * 16 + p] * C[j * 16 + p];
    M[i][j] = s;
  }
  __syncthreads();
  for (int c = 0; c < 16; ++c) {
    if (tid == 0) {
      float s = M[c][c];
      for (int p = 0; p < c; ++p) s -= L[c][p] * L[c][p];
      L[c][c] = sqrtf(s);
    }
    __syncthreads();
    if (tid > c && tid < 16) {
      float s = M[tid][c];
      for (int p = 0; p < c; ++p) s -= L[tid][p] * L[c][p];
      L[tid][c] = s / L[c][c];
    }
    __syncthreads();
  }
  if (tid < 16) {
    for (int r = 0; r < 16; ++r) {
      float s = (r == tid) ? 1.f : 0.f;
      for (int p = tid; p < r; ++p) s -= L[r][p] * X[p][tid];
      X[r][tid] = (r >= tid) ? s / L[r][r] : 0.f;
    }
  }
  __syncthreads();
  linv[i * 16 + j] = X[i][j];
  if (tid == 0) {
    float s = 0.f;
    for (int d = 0; d < 16; ++d) s += logf(L[d][d]);
    *logdet = 2.f * s;
  }
}

// ---------------------------------------------------------------------------
// encoder: h = leaky(x@W1+b1); enc = h@W2+b2; z = mu + exp(.5 lv)*eps; logq acc
// ---------------------------------------------------------------------------
__global__ __launch_bounds__(256) void enc_kernel(
    const float* __restrict__ x, const float* __restrict__ eps,
    const float* __restrict__ W1, const float* __restrict__ b1,
    const float* __restrict__ W2, const float* __restrict__ b2,
    float* __restrict__ z_out, float* __restrict__ ws) {
  __shared__ __align__(16) float xT[128][20];
  __shared__ __align__(16) float hs[16][260];
  __shared__ float sred;
  int tid = threadIdx.x;
  long row0 = (long)blockIdx.x * 16;
  if (tid == 0) sred = 0.f;
  const float* xblk = x + row0 * DOBS;
  #pragma unroll
  for (int q = 0; q < 8; ++q) {
    int e = tid + q * 256;
    xT[e & 127][e >> 7] = xblk[e];
  }
  __syncthreads();
  int tr = tid >> 6, tc = tid & 63;
  float acc[4][4];
  #pragma unroll
  for (int rr = 0; rr < 4; ++rr)
    #pragma unroll
    for (int cc = 0; cc < 4; ++cc) acc[rr][cc] = 0.f;
  #pragma unroll 4
  for (int d = 0; d < 128; ++d) {
    float4 av = *(const float4*)&xT[d][4 * tr];
    float4 bv = *(const float4*)&W1[d * 256 + 4 * tc];
    float am[4] = {av.x, av.y, av.z, av.w};
    float bm[4] = {bv.x, bv.y, bv.z, bv.w};
    #pragma unroll
    for (int rr = 0; rr < 4; ++rr)
      #pragma unroll
      for (int cc = 0; cc < 4; ++cc) acc[rr][cc] += am[rr] * bm[cc];
  }
  {
    float4 b1v = *(const float4*)&b1[4 * tc];
    float bm[4] = {b1v.x, b1v.y, b1v.z, b1v.w};
    #pragma unroll
    for (int rr = 0; rr < 4; ++rr)
      #pragma unroll
      for (int cc = 0; cc < 4; ++cc)
        hs[4 * tr + rr][4 * tc + cc] = leakyf(acc[rr][cc] + bm[cc]);
  }
  __syncthreads();
  int r = tid >> 4, c = tid & 15;
  float e0 = b2[c], e1 = b2[c + 16];
  const float* W2c = W2 + c;
  #pragma unroll 2
  for (int i4 = 0; i4 < 64; ++i4) {
    float4 h = *(const float4*)&hs[r][4 * i4];
    int ib = i4 * 128;
    e0 += h.x * W2c[ib];      e1 += h.x * W2c[ib + 16];
    e0 += h.y * W2c[ib + 32]; e1 += h.y * W2c[ib + 48];
    e0 += h.z * W2c[ib + 64]; e1 += h.z * W2c[ib + 80];
    e0 += h.w * W2c[ib + 96]; e1 += h.w * W2c[ib + 112];
  }
  long rowg = row0 + r;
  float epsv = eps[rowg * 16 + c];
  float zv = e0 + expf(0.5f * e1) * epsv;
  z_out[rowg * 16 + c] = zv;
  float zz = zv - e0;
  float contrib = e1 + zz * zz * expf(-e1);
  contrib += __shfl_xor(contrib, 1, 64);
  contrib += __shfl_xor(contrib, 2, 64);
  contrib += __shfl_xor(contrib, 4, 64);
  contrib += __shfl_xor(contrib, 8, 64);
  if (c == 0) atomicAdd(&sred, -0.5f * (16.f * LOG2PI_F + contrib));
  __syncthreads();
  if (tid == 0) atomicAdd(&ws[1], sred);
}

// ---------------------------------------------------------------------------
// ev0: ev[b,0,k] from init_mean / Linv0
// ---------------------------------------------------------------------------
__global__ __launch_bounds__(256) void ev0_kernel(const float* __restrict__ z,
                                                  const float* __restrict__ init_mean,
                                                  const float* __restrict__ ws,
                                                  float* __restrict__ ev) {
  int gid = blockIdx.x * 256 + threadIdx.x;
  if (gid >= B_SZ * K_SZ) return;
  int k = gid & 7, b = gid >> 3;
  const float* zr = z + (long)b * T_SZ * 16;
  const float* linv = ws + LINV0_OFF + k * 256;
  float diff[16];
  #pragma unroll
  for (int d = 0; d < 16; ++d) diff[d] = zr[d] - init_mean[k * 16 + d];
  float quad = 0.f;
  #pragma unroll
  for (int i2 = 0; i2 < 16; ++i2) {
    float s = 0.f;
    #pragma unroll
    for (int jj = 0; jj < 16; ++jj) s += linv[i2 * 16 + jj] * diff[jj];
    quad += s * s;
  }
  ev[(long)b * T_SZ * 8 + k] = -0.5f * (16.f * LOG2PI_F + ws[LOGDET0_OFF + k] + quad);
}

// ---------------------------------------------------------------------------
// evt (bf16 MFMA): per k, M = softplus(Z@Wt1k + bt1k)@Wt2k + bt2k, then
// ev[.,t+1,k] = mvn(z_next - M). Block = 256 thr (4 waves), 64 rows, one k.
// Only the HW-verified 16x16x32_bf16 shape is used (K=16 sides zero-padded).
// LDS layouts bank-padded: row strides 24 / 264 shorts (2-way max = free).
// ---------------------------------------------------------------------------
__global__ __launch_bounds__(256) void evt_kernel(
    const float* __restrict__ z, const float* __restrict__ Wt1,
    const float* __restrict__ bt1, const float* __restrict__ Wt2,
    const float* __restrict__ bt2, const float* __restrict__ ws,
    float* __restrict__ ev) {
  __shared__ __align__(16) unsigned short w1t[256 * 24];    // [i][d] = bf16(Wt1k[d][i])
  __shared__ __align__(16) unsigned short w2t[16 * 264];    // [d2][h] = bf16(Wt2k[h][d2])
  __shared__ __align__(16) unsigned short hbuf[4 * 16 * 264]; // per-wave H tile [r][h]
  __shared__ __align__(16) unsigned short dbuf[4 * 16 * 24];  // per-wave diff [r][d]
  __shared__ __align__(16) unsigned short linvb[16 * 24];   // [i][j] = bf16(Linv[i][j])
  int tid = threadIdx.x;
  int k = blockIdx.y;
  const float* w1g = Wt1 + k * 4096;
  const float* w2g = Wt2 + k * 4096;
  #pragma unroll
  for (int it = 0; it < 16; ++it)
    w1t[tid * 24 + it] = f2bf(w1g[it * 256 + tid]);   // i=tid, d=it
  #pragma unroll
  for (int it = 0; it < 16; ++it) {
    int e = tid + it * 256;
    w2t[(e & 15) * 264 + (e >> 4)] = f2bf(w2g[e]);    // d2=e&15, h=e>>4
  }
  { int i = tid >> 4, j = tid & 15;
    linvb[i * 24 + j] = f2bf(ws[LINVT_OFF + k * 256 + tid]); }
  float logdetk = ws[LOGDETT_OFF + k];
  __syncthreads();

  int wid = tid >> 6;
  int lane = tid & 63;
  int m = lane & 15, quad = lane >> 4;
  long wave_base = (long)blockIdx.x * 64 + wid * 16;
  unsigned short* hb = hbuf + wid * (16 * 264);
  unsigned short* db = dbuf + wid * (16 * 24);

  // A-frag for GEMM1: A[r=m][d=quad*8+j], quads 2,3 are K-padding (zero)
  short8 za = (short8)0;
  if (quad < 2) {
    const float* zp = z + (wave_base + m) * 16 + quad * 8;
    float4 f0 = *(const float4*)zp;
    float4 f1 = *(const float4*)(zp + 4);
    za[0] = (short)f2bf(f0.x); za[1] = (short)f2bf(f0.y);
    za[2] = (short)f2bf(f0.z); za[3] = (short)f2bf(f0.w);
    za[4] = (short)f2bf(f1.x); za[5] = (short)f2bf(f1.y);
    za[6] = (short)f2bf(f1.z); za[7] = (short)f2bf(f1.w);
  }

  // GEMM1 + softplus, col-tile by col-tile
  const float* bt1g = bt1 + k * 256;
  #pragma unroll 4
  for (int c = 0; c < 16; ++c) {
    short8 bfrag = (short8)0;
    if (quad < 2) bfrag = *(const short8*)&w1t[(c * 16 + m) * 24 + quad * 8];
    float bias = bt1g[c * 16 + m];
    floatx4 a1 = {bias, bias, bias, bias};
    a1 = __builtin_amdgcn_mfma_f32_16x16x32_bf16(za, bfrag, a1, 0, 0, 0);
    #pragma unroll
    for (int g = 0; g < 4; ++g) {
      float v = a1[g];
      float t = __expf(-fabsf(v));
      float sp = fmaxf(v, 0.f) + __logf(1.f + t);
      hb[(quad * 4 + g) * 264 + c * 16 + m] = f2bf(sp);   // C-layout: col=m, row=quad*4+g
    }
  }

  // GEMM2: mean = H @ Wt2k + bt2 (accumulator seeded with bias)
  float btv = bt2[k * 16 + m];
  floatx4 a2 = {btv, btv, btv, btv};
  #pragma unroll
  for (int kt = 0; kt < 8; ++kt) {
    short8 ha = *(const short8*)&hb[m * 264 + kt * 32 + quad * 8];
    short8 wb = *(const short8*)&w2t[m * 264 + kt * 32 + quad * 8];
    a2 = __builtin_amdgcn_mfma_f32_16x16x32_bf16(ha, wb, a2, 0, 0, 0);
  }

  // diff = z_next - mean (fp32), to LDS in A-layout
  #pragma unroll
  for (int g = 0; g < 4; ++g) {
    long grow = wave_base + quad * 4 + g;
    float znx = (grow + 1 < ROWS_A) ? z[(grow + 1) * 16 + m] : 0.f;
    db[(quad * 4 + g) * 24 + m] = f2bf(znx - a2[g]);
  }
  // GEMM3: Sol = Diff @ Linv^T  (B[k=j][n=i] = Linv[i][j])
  short8 da = (short8)0, lb = (short8)0;
  if (quad < 2) {
    da = *(const short8*)&db[m * 24 + quad * 8];
    lb = *(const short8*)&linvb[m * 24 + quad * 8];
  }
  floatx4 a3 = {0.f, 0.f, 0.f, 0.f};
  a3 = __builtin_amdgcn_mfma_f32_16x16x32_bf16(da, lb, a3, 0, 0, 0);
  #pragma unroll
  for (int g = 0; g < 4; ++g) {
    float v = a3[g];
    v = v * v;
    v += __shfl_xor(v, 1, 64);
    v += __shfl_xor(v, 2, 64);
    v += __shfl_xor(v, 4, 64);
    v += __shfl_xor(v, 8, 64);
    long grow = wave_base + quad * 4 + g;
    if (m == 0 && (grow & 511) != 511)
      ev[(grow + 1) * 8 + k] = -0.5f * (16.f * LOG2PI_F + logdetk + v);
  }
}

// ---------------------------------------------------------------------------
// HMM forward, scaled linear-space (see r3 notes). 8 lanes/batch, 8 batches/wave.
// ---------------------------------------------------------------------------
__global__ __launch_bounds__(64) void hmm_kernel(const float* __restrict__ Q,
                                                 const float* __restrict__ pi,
                                                 const float* __restrict__ ev,
                                                 float* __restrict__ ws) {
  int lane = threadIdx.x & 63;
  int g = lane >> 3, i = lane & 7;
  int b = blockIdx.x * 8 + g;

  float q[8];
  #pragma unroll
  for (int d = 0; d < 8; ++d) {
    int j = (i + d) & 7;
    float mr = Q[j * 8 + 0];
    #pragma unroll
    for (int c = 1; c < 8; ++c) mr = fmaxf(mr, Q[j * 8 + c]);
    float rs = 0.f;
    #pragma unroll
    for (int c = 0; c < 8; ++c) rs += __expf(Q[j * 8 + c] - mr);
    q[d] = __expf(Q[j * 8 + i] - mr) / rs;
  }
  float mp = pi[0];
  #pragma unroll
  for (int c = 1; c < 8; ++c) mp = fmaxf(mp, pi[c]);
  float sp = 0.f;
  #pragma unroll
  for (int c = 0; c < 8; ++c) sp += __expf(pi[c] - mp);
  float lpi = pi[i] - mp - __logf(sp);

  const float* evb = ev + (long)b * 4096;
  float lp0 = evb[i] + lpi;
  float m0 = lp0;
  m0 = fmaxf(m0, __shfl_xor(m0, 1, 64));
  m0 = fmaxf(m0, __shfl_xor(m0, 2, 64));
  m0 = fmaxf(m0, __shfl_xor(m0, 4, 64));
  float u = __expf(lp0 - m0);
  double acc = (double)m0;

  int base = lane & 56;
  int x1 = base | ((i + 1) & 7), x2 = base | ((i + 2) & 7), x3 = base | ((i + 3) & 7);
  int x4 = base | ((i + 4) & 7), x5 = base | ((i + 5) & 7), x6 = base | ((i + 6) & 7);
  int x7 = base | ((i + 7) & 7);

  float e1 = evb[8 + i];
  float mt = e1;
  mt = fmaxf(mt, __shfl_xor(mt, 1, 64));
  mt = fmaxf(mt, __shfl_xor(mt, 2, 64));
  mt = fmaxf(mt, __shfl_xor(mt, 4, 64));
  float f_nx = __expf(e1 - mt);
  float mt_nx = mt;

  for (int t = 1; t < 512; ++t) {
    float f = f_nx;
    float mtc = mt_nx;
    if (t < 511) {
      float e = evb[(t + 1) * 8 + i];
      float m2 = e;
      m2 = fmaxf(m2, __shfl_xor(m2, 1, 64));
      m2 = fmaxf(m2, __shfl_xor(m2, 2, 64));
      m2 = fmaxf(m2, __shfl_xor(m2, 4, 64));
      f_nx = __expf(e - m2);
      mt_nx = m2;
    }
    float a1 = __shfl(u, x1, 64), a2 = __shfl(u, x2, 64), a3 = __shfl(u, x3, 64);
    float a4 = __shfl(u, x4, 64), a5 = __shfl(u, x5, 64), a6 = __shfl(u, x6, 64);
    float a7 = __shfl(u, x7, 64);
    float s = ((q[0] * u + q[1] * a1) + (q[2] * a2 + q[3] * a3))
            + ((q[4] * a4 + q[5] * a5) + (q[6] * a6 + q[7] * a7));
    u = f * s;
    acc += (double)mtc;
    if ((t & 15) == 0) {
      float rs = u;
      rs += __shfl_xor(rs, 1, 64);
      rs += __shfl_xor(rs, 2, 64);
      rs += __shfl_xor(rs, 4, 64);
      acc += (double)__logf(rs);
      u = u / rs;
    }
  }
  float rs = u;
  rs += __shfl_xor(rs, 1, 64);
  rs += __shfl_xor(rs, 2, 64);
  rs += __shfl_xor(rs, 4, 64);
  float logZ = (float)(acc + (double)__logf(rs));
  if (i == 0) atomicAdd(&ws[2], logZ);
}

// ---------------------------------------------------------------------------
// decoder: x_hat = leaky(z@Wd1+bd1)@Wd2+bd2 ; recon accumulation
// ---------------------------------------------------------------------------
__global__ __launch_bounds__(256) void dec_kernel(
    const float* __restrict__ x, const float* __restrict__ z,
    const float* __restrict__ Wd1, const float* __restrict__ bd1,
    const float* __restrict__ Wd2, const float* __restrict__ bd2,
    float* __restrict__ xhat, float* __restrict__ ws) {
  __shared__ __align__(16) float zT[16][20];
  __shared__ __align__(16) float h2T[256][20];
  __shared__ float sred;
  int tid = threadIdx.x;
  long row0 = (long)blockIdx.x * 16;
  if (tid == 0) sred = 0.f;
  {
    int r = tid >> 4, d = tid & 15;
    zT[d][r] = z[(row0 + r) * 16 + d];
  }
  __syncthreads();
  int tr = tid >> 6, tc = tid & 63;
  float acc[4][4];
  #pragma unroll
  for (int rr = 0; rr < 4; ++rr)
    #pragma unroll
    for (int cc = 0; cc < 4; ++cc) acc[rr][cc] = 0.f;
  #pragma unroll
  for (int d = 0; d < 16; ++d) {
    float4 av = *(const float4*)&zT[d][4 * tr];
    float4 bv = *(const float4*)&Wd1[d * 256 + 4 * tc];
    float am[4] = {av.x, av.y, av.z, av.w};
    float bm[4] = {bv.x, bv.y, bv.z, bv.w};
    #pragma unroll
    for (int rr = 0; rr < 4; ++rr)
      #pragma unroll
      for (int cc = 0; cc < 4; ++cc) acc[rr][cc] += am[rr] * bm[cc];
  }
  {
    float4 bv = *(const float4*)&bd1[4 * tc];
    float bm[4] = {bv.x, bv.y, bv.z, bv.w};
    #pragma unroll
    for (int rr = 0; rr < 4; ++rr)
      #pragma unroll
      for (int cc = 0; cc < 4; ++cc)
        h2T[4 * tc + cc][4 * tr + rr] = leakyf(acc[rr][cc] + bm[cc]);
  }
  __syncthreads();
  float acc2[4][2];
  #pragma unroll
  for (int rr = 0; rr < 4; ++rr) { acc2[rr][0] = 0.f; acc2[rr][1] = 0.f; }
  #pragma unroll 2
  for (int i = 0; i < 256; ++i) {
    float4 av = *(const float4*)&h2T[i][4 * tr];
    float w0 = Wd2[i * 128 + tc];
    float w1_ = Wd2[i * 128 + tc + 64];
    float am[4] = {av.x, av.y, av.z, av.w};
    #pragma unroll
    for (int rr = 0; rr < 4; ++rr) {
      acc2[rr][0] += am[rr] * w0;
      acc2[rr][1] += am[rr] * w1_;
    }
  }
  float C0 = -0.5f * logf(6.2831853071795864f * VAR_F);
  float rsum = 0.f;
  #pragma unroll
  for (int rr = 0; rr < 4; ++rr) {
    long row = row0 + 4 * tr + rr;
    #pragma unroll
    for (int cc = 0; cc < 2; ++cc) {
      int col = tc + cc * 64;
      float xh = acc2[rr][cc] + bd2[col];
      xhat[row * 128 + col] = xh;
      float d_ = x[row * 128 + col] - xh;
      rsum += C0 - d_ * d_ * (0.5f / VAR_F);
    }
  }
  #pragma unroll
  for (int off = 1; off < 64; off <<= 1) rsum += __shfl_xor(rsum, off, 64);
  if ((tid & 63) == 0) atomicAdd(&sred, rsum);
  __syncthreads();
  if (tid == 0) atomicAdd(&ws[0], sred);
}

__global__ void fin_kernel(const float* __restrict__ ws, float* __restrict__ out) {
  float loss = -((ws[0] - ws[1] + ws[2]) * (1.f / 64.f));
  out[LOSS_OFF] = loss;
}

extern "C" void kernel_launch(void* const* d_in, const int* in_sizes, int n_in,
                              void* d_out, int out_size, void* d_ws, size_t ws_size,
                              hipStream_t stream) {
  (void)in_sizes; (void)n_in; (void)out_size; (void)ws_size;
  const float* x   = (const float*)d_in[0];
  const float* eps = (const float*)d_in[1];
  const float* W1  = (const float*)d_in[2];
  const float* b1  = (const float*)d_in[3];
  const float* W2  = (const float*)d_in[4];
  const float* b2  = (const float*)d_in[5];
  const float* Wt1 = (const float*)d_in[6];
  const float* bt1 = (const float*)d_in[7];
  const float* Wt2 = (const float*)d_in[8];
  const float* bt2 = (const float*)d_in[9];
  const float* Wd1 = (const float*)d_in[10];
  const float* bd1 = (const float*)d_in[11];
  const float* Wd2 = (const float*)d_in[12];
  const float* bd2 = (const float*)d_in[13];
  const float* Q   = (const float*)d_in[14];
  const float* pi  = (const float*)d_in[15];
  const float* im  = (const float*)d_in[16];
  const float* ic  = (const float*)d_in[17];
  const float* cv  = (const float*)d_in[18];
  float* out = (float*)d_out;
  float* ws  = (float*)d_ws;
  float* z_out = out + Z_OUT_OFF;
  float* ev = out;  // stage ev in x_hat region; consumed by hmm before dec overwrites

  hipMemsetAsync(ws, 0, 16, stream);
  prep_kernel<<<16, 256, 0, stream>>>(ic, cv, ws);
  enc_kernel<<<2048, 256, 0, stream>>>(x, eps, W1, b1, W2, b2, z_out, ws);
  ev0_kernel<<<2, 256, 0, stream>>>(z_out, im, ws, ev);
  evt_kernel<<<dim3(512, 8), 256, 0, stream>>>(z_out, Wt1, bt1, Wt2, bt2, ws, ev);
  hmm_kernel<<<8, 64, 0, stream>>>(Q, pi, ev, ws);
  dec_kernel<<<2048, 256, 0, stream>>>(x, z_out, Wd1, bd1, Wd2, bd2, out, ws);
  fin_kernel<<<1, 1, 0, stream>>>(ws, out);
}

// Round 5
// 364.524 us; speedup vs baseline: 1.9652x; 1.2655x over previous
//
#include <hip/hip_runtime.h>
#include <math.h>

#define B_SZ   64
#define T_SZ   512
#define DOBS   128
#define DLAT   16
#define DHID   256
#define K_SZ   8
#define ROWS_T 32704   // B*(T-1)
#define ROWS_A 32768   // B*T (evt computes all, last row per batch discarded)

#define LOG2PI_F 1.8378770664093453f
#define VAR_F    5.0e-4f

// ws float offsets
#define LINV0_OFF   16
#define LOGDET0_OFF 2064
#define LINVT_OFF   2080
#define LOGDETT_OFF 4128
// ws[0]=recon_sum ws[1]=logq_sum ws[2]=msm_sum

#define Z_OUT_OFF   4194304   // B*T*DOBS
#define LOSS_OFF    4718592   // + B*T*DLAT
// staging inside x_hat region of d_out (consumed before dec overwrites):
// evT[b][k][t]  at out[0 .. 262144)
// pbuf          at out[262144 .. 327680)   64 b x 16 c x 64 entries
// accbuf        at out[327680 .. 328704)
#define PBUF_OFF  262144
#define ACC_OFF   327680

typedef __attribute__((ext_vector_type(8))) short short8;
typedef __attribute__((ext_vector_type(4))) float floatx4;

__device__ __forceinline__ float leakyf(float v) { return v > 0.f ? v : 0.01f * v; }
__device__ __forceinline__ unsigned short f2bf(float f) {
  union { float f; unsigned int u; } v; v.f = f;
  unsigned int lsb = (v.u >> 16) & 1;
  v.u += 0x7fffu + lsb;   // round-to-nearest-even
  return (unsigned short)(v.u >> 16);
}

// ---------------------------------------------------------------------------
// prep: per-k Cholesky of C C^T + 1e-6 I, then Linv (lower-tri inverse), logdet.
// ---------------------------------------------------------------------------
__global__ __launch_bounds__(256) void prep_kernel(const float* __restrict__ init_cov,
                                                   const float* __restrict__ covs,
                                                   float* __restrict__ ws) {
  __shared__ float M[16][16];
  __shared__ float L[16][16];
  __shared__ float X[16][17];
  int job = blockIdx.x;
  const float* C = (job < 8) ? (init_cov + job * 256) : (covs + (job - 8) * 256);
  float* linv = ws + ((job < 8) ? (LINV0_OFF + job * 256) : (LINVT_OFF + (job - 8) * 256));
  float* logdet = ws + ((job < 8) ? (LOGDET0_OFF + job) : (LOGDETT_OFF + (job - 8)));
  int tid = threadIdx.x;
  int i = tid >> 4, j = tid & 15;
  {
    float s = (i == j) ? 1e-6f : 0.f;
    #pragma unroll
    for (int p = 0; p < 16; ++p) s += C[i * 16 + p] * C[j * 16 + p];
    M[i][j] = s;
  }
  __syncthreads();
  for (int c = 0; c < 16; ++c) {
    if (tid == 0) {
      float s = M[c][c];
      for (int p = 0; p < c; ++p) s -= L[c][p] * L[c][p];
      L[c][c] = sqrtf(s);
    }
    __syncthreads();
    if (tid > c && tid < 16) {
      float s = M[tid][c];
      for (int p = 0; p < c; ++p) s -= L[tid][p] * L[c][p];
      L[tid][c] = s / L[c][c];
    }
    __syncthreads();
  }
  if (tid < 16) {
    for (int r = 0; r < 16; ++r) {
      float s = (r == tid) ? 1.f : 0.f;
      for (int p = tid; p < r; ++p) s -= L[r][p] * X[p][tid];
      X[r][tid] = (r >= tid) ? s / L[r][r] : 0.f;
    }
  }
  __syncthreads();
  linv[i * 16 + j] = X[i][j];
  if (tid == 0) {
    float s = 0.f;
    for (int d = 0; d < 16; ++d) s += logf(L[d][d]);
    *logdet = 2.f * s;
  }
}

// ---------------------------------------------------------------------------
// encoder: h = leaky(x@W1+b1); enc = h@W2+b2; z = mu + exp(.5 lv)*eps; logq acc
// ---------------------------------------------------------------------------
__global__ __launch_bounds__(256) void enc_kernel(
    const float* __restrict__ x, const float* __restrict__ eps,
    const float* __restrict__ W1, const float* __restrict__ b1,
    const float* __restrict__ W2, const float* __restrict__ b2,
    float* __restrict__ z_out, float* __restrict__ ws) {
  __shared__ __align__(16) float xT[128][20];
  __shared__ __align__(16) float hs[16][260];
  __shared__ float sred;
  int tid = threadIdx.x;
  long row0 = (long)blockIdx.x * 16;
  if (tid == 0) sred = 0.f;
  const float* xblk = x + row0 * DOBS;
  #pragma unroll
  for (int q = 0; q < 8; ++q) {
    int e = tid + q * 256;
    xT[e & 127][e >> 7] = xblk[e];
  }
  __syncthreads();
  int tr = tid >> 6, tc = tid & 63;
  float acc[4][4];
  #pragma unroll
  for (int rr = 0; rr < 4; ++rr)
    #pragma unroll
    for (int cc = 0; cc < 4; ++cc) acc[rr][cc] = 0.f;
  #pragma unroll 4
  for (int d = 0; d < 128; ++d) {
    float4 av = *(const float4*)&xT[d][4 * tr];
    float4 bv = *(const float4*)&W1[d * 256 + 4 * tc];
    float am[4] = {av.x, av.y, av.z, av.w};
    float bm[4] = {bv.x, bv.y, bv.z, bv.w};
    #pragma unroll
    for (int rr = 0; rr < 4; ++rr)
      #pragma unroll
      for (int cc = 0; cc < 4; ++cc) acc[rr][cc] += am[rr] * bm[cc];
  }
  {
    float4 b1v = *(const float4*)&b1[4 * tc];
    float bm[4] = {b1v.x, b1v.y, b1v.z, b1v.w};
    #pragma unroll
    for (int rr = 0; rr < 4; ++rr)
      #pragma unroll
      for (int cc = 0; cc < 4; ++cc)
        hs[4 * tr + rr][4 * tc + cc] = leakyf(acc[rr][cc] + bm[cc]);
  }
  __syncthreads();
  int r = tid >> 4, c = tid & 15;
  float e0 = b2[c], e1 = b2[c + 16];
  const float* W2c = W2 + c;
  #pragma unroll 2
  for (int i4 = 0; i4 < 64; ++i4) {
    float4 h = *(const float4*)&hs[r][4 * i4];
    int ib = i4 * 128;
    e0 += h.x * W2c[ib];      e1 += h.x * W2c[ib + 16];
    e0 += h.y * W2c[ib + 32]; e1 += h.y * W2c[ib + 48];
    e0 += h.z * W2c[ib + 64]; e1 += h.z * W2c[ib + 80];
    e0 += h.w * W2c[ib + 96]; e1 += h.w * W2c[ib + 112];
  }
  long rowg = row0 + r;
  float epsv = eps[rowg * 16 + c];
  float zv = e0 + expf(0.5f * e1) * epsv;
  z_out[rowg * 16 + c] = zv;
  float zz = zv - e0;
  float contrib = e1 + zz * zz * expf(-e1);
  contrib += __shfl_xor(contrib, 1, 64);
  contrib += __shfl_xor(contrib, 2, 64);
  contrib += __shfl_xor(contrib, 4, 64);
  contrib += __shfl_xor(contrib, 8, 64);
  if (c == 0) atomicAdd(&sred, -0.5f * (16.f * LOG2PI_F + contrib));
  __syncthreads();
  if (tid == 0) atomicAdd(&ws[1], sred);
}

// ---------------------------------------------------------------------------
// ev0: evT[b][k][0] from init_mean / Linv0
// ---------------------------------------------------------------------------
__global__ __launch_bounds__(256) void ev0_kernel(const float* __restrict__ z,
                                                  const float* __restrict__ init_mean,
                                                  const float* __restrict__ ws,
                                                  float* __restrict__ evT) {
  int gid = blockIdx.x * 256 + threadIdx.x;
  if (gid >= B_SZ * K_SZ) return;
  int k = gid & 7, b = gid >> 3;
  const float* zr = z + (long)b * T_SZ * 16;
  const float* linv = ws + LINV0_OFF + k * 256;
  float diff[16];
  #pragma unroll
  for (int d = 0; d < 16; ++d) diff[d] = zr[d] - init_mean[k * 16 + d];
  float quad = 0.f;
  #pragma unroll
  for (int i2 = 0; i2 < 16; ++i2) {
    float s = 0.f;
    #pragma unroll
    for (int jj = 0; jj < 16; ++jj) s += linv[i2 * 16 + jj] * diff[jj];
    quad += s * s;
  }
  evT[(long)b * 4096 + (long)k * 512] =
      -0.5f * (16.f * LOG2PI_F + ws[LOGDET0_OFF + k] + quad);
}

// ---------------------------------------------------------------------------
// evt (bf16 MFMA): per k, M = softplus(Z@Wt1k + bt1k)@Wt2k + bt2k, then
// evT[b][k][t+1] = mvn(z_next - M). Block = 256 thr (4 waves), 64 rows, one k.
// ---------------------------------------------------------------------------
__global__ __launch_bounds__(256) void evt_kernel(
    const float* __restrict__ z, const float* __restrict__ Wt1,
    const float* __restrict__ bt1, const float* __restrict__ Wt2,
    const float* __restrict__ bt2, const float* __restrict__ ws,
    float* __restrict__ evT) {
  __shared__ __align__(16) unsigned short w1t[256 * 24];    // [i][d] = bf16(Wt1k[d][i])
  __shared__ __align__(16) unsigned short w2t[16 * 264];    // [d2][h] = bf16(Wt2k[h][d2])
  __shared__ __align__(16) unsigned short hbuf[4 * 16 * 264]; // per-wave H tile [r][h]
  __shared__ __align__(16) unsigned short dbuf[4 * 16 * 24];  // per-wave diff [r][d]
  __shared__ __align__(16) unsigned short linvb[16 * 24];   // [i][j] = bf16(Linv[i][j])
  int tid = threadIdx.x;
  int k = blockIdx.y;
  const float* w1g = Wt1 + k * 4096;
  const float* w2g = Wt2 + k * 4096;
  #pragma unroll
  for (int it = 0; it < 16; ++it)
    w1t[tid * 24 + it] = f2bf(w1g[it * 256 + tid]);   // i=tid, d=it
  #pragma unroll
  for (int it = 0; it < 16; ++it) {
    int e = tid + it * 256;
    w2t[(e & 15) * 264 + (e >> 4)] = f2bf(w2g[e]);    // d2=e&15, h=e>>4
  }
  { int i = tid >> 4, j = tid & 15;
    linvb[i * 24 + j] = f2bf(ws[LINVT_OFF + k * 256 + tid]); }
  float logdetk = ws[LOGDETT_OFF + k];
  __syncthreads();

  int wid = tid >> 6;
  int lane = tid & 63;
  int m = lane & 15, quad = lane >> 4;
  long wave_base = (long)blockIdx.x * 64 + wid * 16;
  unsigned short* hb = hbuf + wid * (16 * 264);
  unsigned short* db = dbuf + wid * (16 * 24);

  short8 za = (short8)0;
  if (quad < 2) {
    const float* zp = z + (wave_base + m) * 16 + quad * 8;
    float4 f0 = *(const float4*)zp;
    float4 f1 = *(const float4*)(zp + 4);
    za[0] = (short)f2bf(f0.x); za[1] = (short)f2bf(f0.y);
    za[2] = (short)f2bf(f0.z); za[3] = (short)f2bf(f0.w);
    za[4] = (short)f2bf(f1.x); za[5] = (short)f2bf(f1.y);
    za[6] = (short)f2bf(f1.z); za[7] = (short)f2bf(f1.w);
  }

  const float* bt1g = bt1 + k * 256;
  #pragma unroll 4
  for (int c = 0; c < 16; ++c) {
    short8 bfrag = (short8)0;
    if (quad < 2) bfrag = *(const short8*)&w1t[(c * 16 + m) * 24 + quad * 8];
    float bias = bt1g[c * 16 + m];
    floatx4 a1 = {bias, bias, bias, bias};
    a1 = __builtin_amdgcn_mfma_f32_16x16x32_bf16(za, bfrag, a1, 0, 0, 0);
    #pragma unroll
    for (int g = 0; g < 4; ++g) {
      float v = a1[g];
      float t = __expf(-fabsf(v));
      float sp = fmaxf(v, 0.f) + __logf(1.f + t);
      hb[(quad * 4 + g) * 264 + c * 16 + m] = f2bf(sp);
    }
  }

  float btv = bt2[k * 16 + m];
  floatx4 a2 = {btv, btv, btv, btv};
  #pragma unroll
  for (int kt = 0; kt < 8; ++kt) {
    short8 ha = *(const short8*)&hb[m * 264 + kt * 32 + quad * 8];
    short8 wb = *(const short8*)&w2t[m * 264 + kt * 32 + quad * 8];
    a2 = __builtin_amdgcn_mfma_f32_16x16x32_bf16(ha, wb, a2, 0, 0, 0);
  }

  #pragma unroll
  for (int g = 0; g < 4; ++g) {
    long grow = wave_base + quad * 4 + g;
    float znx = (grow + 1 < ROWS_A) ? z[(grow + 1) * 16 + m] : 0.f;
    db[(quad * 4 + g) * 24 + m] = f2bf(znx - a2[g]);
  }
  short8 da = (short8)0, lb = (short8)0;
  if (quad < 2) {
    da = *(const short8*)&db[m * 24 + quad * 8];
    lb = *(const short8*)&linvb[m * 24 + quad * 8];
  }
  floatx4 a3 = {0.f, 0.f, 0.f, 0.f};
  a3 = __builtin_amdgcn_mfma_f32_16x16x32_bf16(da, lb, a3, 0, 0, 0);
  #pragma unroll
  for (int g = 0; g < 4; ++g) {
    float v = a3[g];
    v = v * v;
    v += __shfl_xor(v, 1, 64);
    v += __shfl_xor(v, 2, 64);
    v += __shfl_xor(v, 4, 64);
    v += __shfl_xor(v, 8, 64);
    long grow = wave_base + quad * 4 + g;
    if (m == 0 && (grow & 511) != 511) {
      long r1 = grow + 1;
      evT[(r1 >> 9) * 4096 + (long)k * 512 + (r1 & 511)] =
          -0.5f * (16.f * LOG2PI_F + logdetk + v);
    }
  }
}

// ---------------------------------------------------------------------------
// HMM forward as a parallel scan over 8x8 transition matrices.
// Stage 1: 64 batches x 16 chunks of 32 transitions; one wave per chunk,
// lane=(i,j) holds P[i][j] of the chunk product  P = M_{tL-1}...M_{t0},
// M_t = diag(f_t) Qexp, f_t = exp(ev_t - max_i ev_t).  Renorm by 64-lane max
// every 8 multiplies (Qexp column-stochastic -> no overflow; decay bounded).
// ---------------------------------------------------------------------------
__global__ __launch_bounds__(256) void hmm_scan(const float* __restrict__ Q,
                                                const float* __restrict__ evT,
                                                float* __restrict__ pbuf,
                                                float* __restrict__ accbuf) {
  int tid = threadIdx.x;
  int wid = tid >> 6, lane = tid & 63;
  int job = blockIdx.x * 4 + wid;          // 0..1023
  int b = job >> 4, c = job & 15;
  int i = lane >> 3, j = lane & 7;

  // qp[p] = Qexp[i][p] = softmax(Q[p,:])[i]
  float qp[8];
  #pragma unroll
  for (int p = 0; p < 8; ++p) {
    float mr = Q[p * 8 + 0];
    #pragma unroll
    for (int cc = 1; cc < 8; ++cc) mr = fmaxf(mr, Q[p * 8 + cc]);
    float rs = 0.f;
    #pragma unroll
    for (int cc = 0; cc < 8; ++cc) rs += __expf(Q[p * 8 + cc] - mr);
    qp[p] = __expf(Q[p * 8 + i] - mr) / rs;
  }
  // qself = Qexp[i][j]
  float qself;
  {
    float mr = Q[j * 8 + 0];
    #pragma unroll
    for (int cc = 1; cc < 8; ++cc) mr = fmaxf(mr, Q[j * 8 + cc]);
    float rs = 0.f;
    #pragma unroll
    for (int cc = 0; cc < 8; ++cc) rs += __expf(Q[j * 8 + cc] - mr);
    qself = __expf(Q[j * 8 + i] - mr) / rs;
  }

  int t0 = 1 + c * 32;
  int L = (c == 15) ? 31 : 32;
  const float* evI = evT + (long)b * 4096 + (long)i * 512 + t0;

  // factors (all off the multiply chain; loads issued upfront by unroll)
  float f[32];
  float accm = 0.f;
  #pragma unroll
  for (int s = 0; s < 32; ++s) {
    float e = (s < L) ? evI[s] : 0.f;
    float m = e;
    m = fmaxf(m, __shfl_xor(m, 8, 64));
    m = fmaxf(m, __shfl_xor(m, 16, 64));
    m = fmaxf(m, __shfl_xor(m, 32, 64));
    f[s] = __expf(e - m);
    if (s < L) accm += m;
  }

  float P = f[0] * qself;   // P = M_{t0}
  #pragma unroll
  for (int s = 1; s < 32; ++s) {
    if (s < L) {
      float a0 = __shfl(P, j,      64);
      float a1 = __shfl(P, 8 + j,  64);
      float a2 = __shfl(P, 16 + j, 64);
      float a3 = __shfl(P, 24 + j, 64);
      float a4 = __shfl(P, 32 + j, 64);
      float a5 = __shfl(P, 40 + j, 64);
      float a6 = __shfl(P, 48 + j, 64);
      float a7 = __shfl(P, 56 + j, 64);
      float sv = ((qp[0] * a0 + qp[1] * a1) + (qp[2] * a2 + qp[3] * a3))
               + ((qp[4] * a4 + qp[5] * a5) + (qp[6] * a6 + qp[7] * a7));
      P = f[s] * sv;
    }
    if ((s & 7) == 7) {
      float mx = P;
      mx = fmaxf(mx, __shfl_xor(mx, 1, 64));
      mx = fmaxf(mx, __shfl_xor(mx, 2, 64));
      mx = fmaxf(mx, __shfl_xor(mx, 4, 64));
      mx = fmaxf(mx, __shfl_xor(mx, 8, 64));
      mx = fmaxf(mx, __shfl_xor(mx, 16, 64));
      mx = fmaxf(mx, __shfl_xor(mx, 32, 64));
      mx = fmaxf(mx, 1e-30f);
      P = P / mx;
      accm += __logf(mx);
    }
  }
  pbuf[(long)job * 64 + lane] = P;
  if (lane == 0) accbuf[job] = accm;
}

// ---------------------------------------------------------------------------
// Stage 2: per batch, fold 16 chunk matrices into u0; one wave per batch.
// u held as u[j] per lane (duplicated over i).
// ---------------------------------------------------------------------------
__global__ __launch_bounds__(512) void hmm_comb(const float* __restrict__ pi,
                                                const float* __restrict__ evT,
                                                const float* __restrict__ pbuf,
                                                const float* __restrict__ accbuf,
                                                float* __restrict__ ws) {
  int tid = threadIdx.x;
  int wid = tid >> 6, lane = tid & 63;
  int b = blockIdx.x * 8 + wid;
  int j = lane & 7;

  // lpi[j]
  float mp = pi[0];
  #pragma unroll
  for (int cc = 1; cc < 8; ++cc) mp = fmaxf(mp, pi[cc]);
  float sp = 0.f;
  #pragma unroll
  for (int cc = 0; cc < 8; ++cc) sp += __expf(pi[cc] - mp);
  float lpi = pi[j] - mp - __logf(sp);

  float lp0 = evT[(long)b * 4096 + (long)j * 512] + lpi;
  float m0 = lp0;
  m0 = fmaxf(m0, __shfl_xor(m0, 1, 64));
  m0 = fmaxf(m0, __shfl_xor(m0, 2, 64));
  m0 = fmaxf(m0, __shfl_xor(m0, 4, 64));
  float u = __expf(lp0 - m0);
  double acc = (double)m0;

  #pragma unroll
  for (int c = 0; c < 16; ++c) {
    float P = pbuf[((long)b * 16 + c) * 64 + lane];
    float contrib = P * u;                 // P[i][j] * u[j]
    contrib += __shfl_xor(contrib, 1, 64);
    contrib += __shfl_xor(contrib, 2, 64);
    contrib += __shfl_xor(contrib, 4, 64); // v[i], duplicated over j
    u = __shfl(contrib, j * 9, 64);        // u[j] = v[j]
    float mxu = u;
    mxu = fmaxf(mxu, __shfl_xor(mxu, 1, 64));
    mxu = fmaxf(mxu, __shfl_xor(mxu, 2, 64));
    mxu = fmaxf(mxu, __shfl_xor(mxu, 4, 64));
    mxu = fmaxf(mxu, 1e-30f);
    u = u / mxu;
    acc += (double)(__logf(mxu) + accbuf[b * 16 + c]);
  }
  float su = u;
  su += __shfl_xor(su, 1, 64);
  su += __shfl_xor(su, 2, 64);
  su += __shfl_xor(su, 4, 64);
  float logZ = (float)(acc + (double)__logf(su));
  if (lane == 0) atomicAdd(&ws[2], logZ);
}

// ---------------------------------------------------------------------------
// decoder: x_hat = leaky(z@Wd1+bd1)@Wd2+bd2 ; recon accumulation
// ---------------------------------------------------------------------------
__global__ __launch_bounds__(256) void dec_kernel(
    const float* __restrict__ x, const float* __restrict__ z,
    const float* __restrict__ Wd1, const float* __restrict__ bd1,
    const float* __restrict__ Wd2, const float* __restrict__ bd2,
    float* __restrict__ xhat, float* __restrict__ ws) {
  __shared__ __align__(16) float zT[16][20];
  __shared__ __align__(16) float h2T[256][20];
  __shared__ float sred;
  int tid = threadIdx.x;
  long row0 = (long)blockIdx.x * 16;
  if (tid == 0) sred = 0.f;
  {
    int r = tid >> 4, d = tid & 15;
    zT[d][r] = z[(row0 + r) * 16 + d];
  }
  __syncthreads();
  int tr = tid >> 6, tc = tid & 63;
  float acc[4][4];
  #pragma unroll
  for (int rr = 0; rr < 4; ++rr)
    #pragma unroll
    for (int cc = 0; cc < 4; ++cc) acc[rr][cc] = 0.f;
  #pragma unroll
  for (int d = 0; d < 16; ++d) {
    float4 av = *(const float4*)&zT[d][4 * tr];
    float4 bv = *(const float4*)&Wd1[d * 256 + 4 * tc];
    float am[4] = {av.x, av.y, av.z, av.w};
    float bm[4] = {bv.x, bv.y, bv.z, bv.w};
    #pragma unroll
    for (int rr = 0; rr < 4; ++rr)
      #pragma unroll
      for (int cc = 0; cc < 4; ++cc) acc[rr][cc] += am[rr] * bm[cc];
  }
  {
    float4 bv = *(const float4*)&bd1[4 * tc];
    float bm[4] = {bv.x, bv.y, bv.z, bv.w};
    #pragma unroll
    for (int rr = 0; rr < 4; ++rr)
      #pragma unroll
      for (int cc = 0; cc < 4; ++cc)
        h2T[4 * tc + cc][4 * tr + rr] = leakyf(acc[rr][cc] + bm[cc]);
  }
  __syncthreads();
  float acc2[4][2];
  #pragma unroll
  for (int rr = 0; rr < 4; ++rr) { acc2[rr][0] = 0.f; acc2[rr][1] = 0.f; }
  #pragma unroll 2
  for (int i = 0; i < 256; ++i) {
    float4 av = *(const float4*)&h2T[i][4 * tr];
    float w0 = Wd2[i * 128 + tc];
    float w1_ = Wd2[i * 128 + tc + 64];
    float am[4] = {av.x, av.y, av.z, av.w};
    #pragma unroll
    for (int rr = 0; rr < 4; ++rr) {
      acc2[rr][0] += am[rr] * w0;
      acc2[rr][1] += am[rr] * w1_;
    }
  }
  float C0 = -0.5f * logf(6.2831853071795864f * VAR_F);
  float rsum = 0.f;
  #pragma unroll
  for (int rr = 0; rr < 4; ++rr) {
    long row = row0 + 4 * tr + rr;
    #pragma unroll
    for (int cc = 0; cc < 2; ++cc) {
      int col = tc + cc * 64;
      float xh = acc2[rr][cc] + bd2[col];
      xhat[row * 128 + col] = xh;
      float d_ = x[row * 128 + col] - xh;
      rsum += C0 - d_ * d_ * (0.5f / VAR_F);
    }
  }
  #pragma unroll
  for (int off = 1; off < 64; off <<= 1) rsum += __shfl_xor(rsum, off, 64);
  if ((tid & 63) == 0) atomicAdd(&sred, rsum);
  __syncthreads();
  if (tid == 0) atomicAdd(&ws[0], sred);
}

__global__ void fin_kernel(const float* __restrict__ ws, float* __restrict__ out) {
  float loss = -((ws[0] - ws[1] + ws[2]) * (1.f / 64.f));
  out[LOSS_OFF] = loss;
}

extern "C" void kernel_launch(void* const* d_in, const int* in_sizes, int n_in,
                              void* d_out, int out_size, void* d_ws, size_t ws_size,
                              hipStream_t stream) {
  (void)in_sizes; (void)n_in; (void)out_size; (void)ws_size;
  const float* x   = (const float*)d_in[0];
  const float* eps = (const float*)d_in[1];
  const float* W1  = (const float*)d_in[2];
  const float* b1  = (const float*)d_in[3];
  const float* W2  = (const float*)d_in[4];
  const float* b2  = (const float*)d_in[5];
  const float* Wt1 = (const float*)d_in[6];
  const float* bt1 = (const float*)d_in[7];
  const float* Wt2 = (const float*)d_in[8];
  const float* bt2 = (const float*)d_in[9];
  const float* Wd1 = (const float*)d_in[10];
  const float* bd1 = (const float*)d_in[11];
  const float* Wd2 = (const float*)d_in[12];
  const float* bd2 = (const float*)d_in[13];
  const float* Q   = (const float*)d_in[14];
  const float* pi  = (const float*)d_in[15];
  const float* im  = (const float*)d_in[16];
  const float* ic  = (const float*)d_in[17];
  const float* cv  = (const float*)d_in[18];
  float* out = (float*)d_out;
  float* ws  = (float*)d_ws;
  float* z_out = out + Z_OUT_OFF;
  float* evT  = out;             // staged in x_hat region, consumed before dec
  float* pbuf = out + PBUF_OFF;
  float* accb = out + ACC_OFF;

  hipMemsetAsync(ws, 0, 16, stream);
  prep_kernel<<<16, 256, 0, stream>>>(ic, cv, ws);
  enc_kernel<<<2048, 256, 0, stream>>>(x, eps, W1, b1, W2, b2, z_out, ws);
  ev0_kernel<<<2, 256, 0, stream>>>(z_out, im, ws, evT);
  evt_kernel<<<dim3(512, 8), 256, 0, stream>>>(z_out, Wt1, bt1, Wt2, bt2, ws, evT);
  hmm_scan<<<256, 256, 0, stream>>>(Q, evT, pbuf, accb);
  hmm_comb<<<8, 512, 0, stream>>>(pi, evT, pbuf, accb, ws);
  dec_kernel<<<2048, 256, 0, stream>>>(x, z_out, Wd1, bd1, Wd2, bd2, out, ws);
  fin_kernel<<<1, 1, 0, stream>>>(ws, out);
}

// Round 6
// 261.852 us; speedup vs baseline: 2.7357x; 1.3921x over previous
//
#include <hip/hip_runtime.h>
#include <math.h>

#define B_SZ   64
#define T_SZ   512
#define DOBS   128
#define DLAT   16
#define DHID   256
#define K_SZ   8
#define ROWS_T 32704   // B*(T-1)
#define ROWS_A 32768   // B*T

#define LOG2PI_F 1.8378770664093453f
#define VAR_F    5.0e-4f

// ws float offsets
#define LINV0_OFF   16
#define LOGDET0_OFF 2064
#define LINVT_OFF   2080
#define LOGDETT_OFF 4128
// ws[0]=recon_sum ws[1]=logq_sum ws[2]=msm_sum

#define Z_OUT_OFF   4194304   // B*T*DOBS
#define LOSS_OFF    4718592   // + B*T*DLAT
// staging inside x_hat region of d_out (consumed before dec overwrites):
#define PBUF_OFF  262144
#define ACC_OFF   327680

typedef __attribute__((ext_vector_type(8))) short short8;
typedef __attribute__((ext_vector_type(4))) float floatx4;

__device__ __forceinline__ float leakyf(float v) { return v > 0.f ? v : 0.01f * v; }
__device__ __forceinline__ unsigned short f2bf(float f) {
  union { float f; unsigned int u; } v; v.f = f;
  unsigned int lsb = (v.u >> 16) & 1;
  v.u += 0x7fffu + lsb;   // round-to-nearest-even
  return (unsigned short)(v.u >> 16);
}

// ---------------------------------------------------------------------------
// prep: per-k Cholesky of C C^T + 1e-6 I, then Linv (lower-tri inverse), logdet.
// ---------------------------------------------------------------------------
__global__ __launch_bounds__(256) void prep_kernel(const float* __restrict__ init_cov,
                                                   const float* __restrict__ covs,
                                                   float* __restrict__ ws) {
  __shared__ float M[16][16];
  __shared__ float L[16][16];
  __shared__ float X[16][17];
  int job = blockIdx.x;
  const float* C = (job < 8) ? (init_cov + job * 256) : (covs + (job - 8) * 256);
  float* linv = ws + ((job < 8) ? (LINV0_OFF + job * 256) : (LINVT_OFF + (job - 8) * 256));
  float* logdet = ws + ((job < 8) ? (LOGDET0_OFF + job) : (LOGDETT_OFF + (job - 8)));
  int tid = threadIdx.x;
  int i = tid >> 4, j = tid & 15;
  {
    float s = (i == j) ? 1e-6f : 0.f;
    #pragma unroll
    for (int p = 0; p < 16; ++p) s += C[i * 16 + p] * C[j * 16 + p];
    M[i][j] = s;
  }
  __syncthreads();
  for (int c = 0; c < 16; ++c) {
    if (tid == 0) {
      float s = M[c][c];
      for (int p = 0; p < c; ++p) s -= L[c][p] * L[c][p];
      L[c][c] = sqrtf(s);
    }
    __syncthreads();
    if (tid > c && tid < 16) {
      float s = M[tid][c];
      for (int p = 0; p < c; ++p) s -= L[tid][p] * L[c][p];
      L[tid][c] = s / L[c][c];
    }
    __syncthreads();
  }
  if (tid < 16) {
    for (int r = 0; r < 16; ++r) {
      float s = (r == tid) ? 1.f : 0.f;
      for (int p = tid; p < r; ++p) s -= L[r][p] * X[p][tid];
      X[r][tid] = (r >= tid) ? s / L[r][r] : 0.f;
    }
  }
  __syncthreads();
  linv[i * 16 + j] = X[i][j];
  if (tid == 0) {
    float s = 0.f;
    for (int d = 0; d < 16; ++d) s += logf(L[d][d]);
    *logdet = 2.f * s;
  }
}

// ---------------------------------------------------------------------------
// encoder (bf16 MFMA): H = leaky(X@W1+b1); [mu,lv] = H@W2+b2; z; logq.
// 256 thr (4 waves), 128 rows/block, 256 blocks (1/CU).
// ---------------------------------------------------------------------------
__global__ __launch_bounds__(256) void enc_kernel(
    const float* __restrict__ x, const float* __restrict__ eps,
    const float* __restrict__ W1, const float* __restrict__ b1,
    const float* __restrict__ W2, const float* __restrict__ b2,
    float* __restrict__ z_out, float* __restrict__ ws) {
  __shared__ __align__(16) unsigned short w1t[256 * 136];   // [n=hid][k=dobs]
  __shared__ __align__(16) unsigned short w2t[32 * 264];    // [n=enc][k=hid]
  __shared__ __align__(16) unsigned short hbuf[4 * 16 * 264];
  __shared__ float sred;
  int tid = threadIdx.x;
  if (tid == 0) sred = 0.f;
  for (int e = tid; e < 32768; e += 256) {      // W1 [128][256]
    int k = e >> 8, n = e & 255;
    w1t[n * 136 + k] = f2bf(W1[e]);
  }
  for (int e = tid; e < 8192; e += 256) {       // W2 [256][32]
    int k = e >> 5, n = e & 31;
    w2t[n * 264 + k] = f2bf(W2[e]);
  }
  __syncthreads();

  int wid = tid >> 6, lane = tid & 63;
  int m = lane & 15, quad = lane >> 4;
  unsigned short* hb = hbuf + wid * (16 * 264);
  float logq_acc = 0.f;

  #pragma unroll
  for (int tile = 0; tile < 2; ++tile) {
    long rowb = (long)blockIdx.x * 128 + wid * 32 + tile * 16;
    // A-frags from x, converted in registers
    short8 xa[4];
    const float* xp = x + (rowb + m) * 128 + quad * 8;
    #pragma unroll
    for (int kt = 0; kt < 4; ++kt) {
      float4 f0 = *(const float4*)(xp + kt * 32);
      float4 f1 = *(const float4*)(xp + kt * 32 + 4);
      short8 v;
      v[0] = (short)f2bf(f0.x); v[1] = (short)f2bf(f0.y);
      v[2] = (short)f2bf(f0.z); v[3] = (short)f2bf(f0.w);
      v[4] = (short)f2bf(f1.x); v[5] = (short)f2bf(f1.y);
      v[6] = (short)f2bf(f1.z); v[7] = (short)f2bf(f1.w);
      xa[kt] = v;
    }
    // GEMM1 + leaky -> hb (C-layout: col=m, row=quad*4+g)
    #pragma unroll 4
    for (int c = 0; c < 16; ++c) {
      float bias = b1[c * 16 + m];
      floatx4 a1 = {bias, bias, bias, bias};
      #pragma unroll
      for (int kt = 0; kt < 4; ++kt) {
        short8 bf = *(const short8*)&w1t[(c * 16 + m) * 136 + kt * 32 + quad * 8];
        a1 = __builtin_amdgcn_mfma_f32_16x16x32_bf16(xa[kt], bf, a1, 0, 0, 0);
      }
      #pragma unroll
      for (int g = 0; g < 4; ++g)
        hb[(quad * 4 + g) * 264 + c * 16 + m] = f2bf(leakyf(a1[g]));
    }
    // GEMM2: 2 col-tiles (mu, logvar)
    float bm0 = b2[m], bm1 = b2[16 + m];
    floatx4 a20 = {bm0, bm0, bm0, bm0};
    floatx4 a21 = {bm1, bm1, bm1, bm1};
    #pragma unroll
    for (int kt = 0; kt < 8; ++kt) {
      short8 ha = *(const short8*)&hb[m * 264 + kt * 32 + quad * 8];
      short8 wb0 = *(const short8*)&w2t[m * 264 + kt * 32 + quad * 8];
      short8 wb1 = *(const short8*)&w2t[(16 + m) * 264 + kt * 32 + quad * 8];
      a20 = __builtin_amdgcn_mfma_f32_16x16x32_bf16(ha, wb0, a20, 0, 0, 0);
      a21 = __builtin_amdgcn_mfma_f32_16x16x32_bf16(ha, wb1, a21, 0, 0, 0);
    }
    // epilogue: z + logq
    #pragma unroll
    for (int g = 0; g < 4; ++g) {
      long row = rowb + quad * 4 + g;
      float mu = a20[g], lv = a21[g];
      float ev = eps[row * 16 + m];
      float zv = mu + __expf(0.5f * lv) * ev;
      z_out[row * 16 + m] = zv;
      float zz = zv - mu;
      logq_acc += lv + zz * zz * __expf(-lv);
    }
  }
  // reduce logq over wave, accumulate
  #pragma unroll
  for (int off = 1; off < 64; off <<= 1) logq_acc += __shfl_xor(logq_acc, off, 64);
  if (lane == 0) atomicAdd(&sred, -0.5f * logq_acc);
  __syncthreads();
  if (tid == 0) atomicAdd(&ws[1], sred - 0.5f * 16.f * LOG2PI_F * 128.f);
}

// ---------------------------------------------------------------------------
// ev0: evT[b][k][0] from init_mean / Linv0
// ---------------------------------------------------------------------------
__global__ __launch_bounds__(256) void ev0_kernel(const float* __restrict__ z,
                                                  const float* __restrict__ init_mean,
                                                  const float* __restrict__ ws,
                                                  float* __restrict__ evT) {
  int gid = blockIdx.x * 256 + threadIdx.x;
  if (gid >= B_SZ * K_SZ) return;
  int k = gid & 7, b = gid >> 3;
  const float* zr = z + (long)b * T_SZ * 16;
  const float* linv = ws + LINV0_OFF + k * 256;
  float diff[16];
  #pragma unroll
  for (int d = 0; d < 16; ++d) diff[d] = zr[d] - init_mean[k * 16 + d];
  float quad = 0.f;
  #pragma unroll
  for (int i2 = 0; i2 < 16; ++i2) {
    float s = 0.f;
    #pragma unroll
    for (int jj = 0; jj < 16; ++jj) s += linv[i2 * 16 + jj] * diff[jj];
    quad += s * s;
  }
  evT[(long)b * 4096 + (long)k * 512] =
      -0.5f * (16.f * LOG2PI_F + ws[LOGDET0_OFF + k] + quad);
}

// ---------------------------------------------------------------------------
// evt (bf16 MFMA): per k, M = softplus(Z@Wt1k + bt1k)@Wt2k + bt2k, then
// evT[b][k][t+1] = mvn(z_next - M). Block = 256 thr (4 waves), 64 rows, one k.
// ---------------------------------------------------------------------------
__global__ __launch_bounds__(256) void evt_kernel(
    const float* __restrict__ z, const float* __restrict__ Wt1,
    const float* __restrict__ bt1, const float* __restrict__ Wt2,
    const float* __restrict__ bt2, const float* __restrict__ ws,
    float* __restrict__ evT) {
  __shared__ __align__(16) unsigned short w1t[256 * 24];
  __shared__ __align__(16) unsigned short w2t[16 * 264];
  __shared__ __align__(16) unsigned short hbuf[4 * 16 * 264];
  __shared__ __align__(16) unsigned short dbuf[4 * 16 * 24];
  __shared__ __align__(16) unsigned short linvb[16 * 24];
  int tid = threadIdx.x;
  int k = blockIdx.y;
  const float* w1g = Wt1 + k * 4096;
  const float* w2g = Wt2 + k * 4096;
  #pragma unroll
  for (int it = 0; it < 16; ++it)
    w1t[tid * 24 + it] = f2bf(w1g[it * 256 + tid]);
  #pragma unroll
  for (int it = 0; it < 16; ++it) {
    int e = tid + it * 256;
    w2t[(e & 15) * 264 + (e >> 4)] = f2bf(w2g[e]);
  }
  { int i = tid >> 4, j = tid & 15;
    linvb[i * 24 + j] = f2bf(ws[LINVT_OFF + k * 256 + tid]); }
  float logdetk = ws[LOGDETT_OFF + k];
  __syncthreads();

  int wid = tid >> 6;
  int lane = tid & 63;
  int m = lane & 15, quad = lane >> 4;
  long wave_base = (long)blockIdx.x * 64 + wid * 16;
  unsigned short* hb = hbuf + wid * (16 * 264);
  unsigned short* db = dbuf + wid * (16 * 24);

  short8 za = (short8)0;
  if (quad < 2) {
    const float* zp = z + (wave_base + m) * 16 + quad * 8;
    float4 f0 = *(const float4*)zp;
    float4 f1 = *(const float4*)(zp + 4);
    za[0] = (short)f2bf(f0.x); za[1] = (short)f2bf(f0.y);
    za[2] = (short)f2bf(f0.z); za[3] = (short)f2bf(f0.w);
    za[4] = (short)f2bf(f1.x); za[5] = (short)f2bf(f1.y);
    za[6] = (short)f2bf(f1.z); za[7] = (short)f2bf(f1.w);
  }

  const float* bt1g = bt1 + k * 256;
  #pragma unroll 4
  for (int c = 0; c < 16; ++c) {
    short8 bfrag = (short8)0;
    if (quad < 2) bfrag = *(const short8*)&w1t[(c * 16 + m) * 24 + quad * 8];
    float bias = bt1g[c * 16 + m];
    floatx4 a1 = {bias, bias, bias, bias};
    a1 = __builtin_amdgcn_mfma_f32_16x16x32_bf16(za, bfrag, a1, 0, 0, 0);
    #pragma unroll
    for (int g = 0; g < 4; ++g) {
      float v = a1[g];
      float t = __expf(-fabsf(v));
      float sp = fmaxf(v, 0.f) + __logf(1.f + t);
      hb[(quad * 4 + g) * 264 + c * 16 + m] = f2bf(sp);
    }
  }

  float btv = bt2[k * 16 + m];
  floatx4 a2 = {btv, btv, btv, btv};
  #pragma unroll
  for (int kt = 0; kt < 8; ++kt) {
    short8 ha = *(const short8*)&hb[m * 264 + kt * 32 + quad * 8];
    short8 wb = *(const short8*)&w2t[m * 264 + kt * 32 + quad * 8];
    a2 = __builtin_amdgcn_mfma_f32_16x16x32_bf16(ha, wb, a2, 0, 0, 0);
  }

  #pragma unroll
  for (int g = 0; g < 4; ++g) {
    long grow = wave_base + quad * 4 + g;
    float znx = (grow + 1 < ROWS_A) ? z[(grow + 1) * 16 + m] : 0.f;
    db[(quad * 4 + g) * 24 + m] = f2bf(znx - a2[g]);
  }
  short8 da = (short8)0, lb = (short8)0;
  if (quad < 2) {
    da = *(const short8*)&db[m * 24 + quad * 8];
    lb = *(const short8*)&linvb[m * 24 + quad * 8];
  }
  floatx4 a3 = {0.f, 0.f, 0.f, 0.f};
  a3 = __builtin_amdgcn_mfma_f32_16x16x32_bf16(da, lb, a3, 0, 0, 0);
  #pragma unroll
  for (int g = 0; g < 4; ++g) {
    float v = a3[g];
    v = v * v;
    v += __shfl_xor(v, 1, 64);
    v += __shfl_xor(v, 2, 64);
    v += __shfl_xor(v, 4, 64);
    v += __shfl_xor(v, 8, 64);
    long grow = wave_base + quad * 4 + g;
    if (m == 0 && (grow & 511) != 511) {
      long r1 = grow + 1;
      evT[(r1 >> 9) * 4096 + (long)k * 512 + (r1 & 511)] =
          -0.5f * (16.f * LOG2PI_F + logdetk + v);
    }
  }
}

// ---------------------------------------------------------------------------
// HMM forward as a parallel scan over 8x8 transition matrices (see r5 notes).
// ---------------------------------------------------------------------------
__global__ __launch_bounds__(256) void hmm_scan(const float* __restrict__ Q,
                                                const float* __restrict__ evT,
                                                float* __restrict__ pbuf,
                                                float* __restrict__ accbuf) {
  int tid = threadIdx.x;
  int wid = tid >> 6, lane = tid & 63;
  int job = blockIdx.x * 4 + wid;
  int b = job >> 4, c = job & 15;
  int i = lane >> 3, j = lane & 7;

  float qp[8];
  #pragma unroll
  for (int p = 0; p < 8; ++p) {
    float mr = Q[p * 8 + 0];
    #pragma unroll
    for (int cc = 1; cc < 8; ++cc) mr = fmaxf(mr, Q[p * 8 + cc]);
    float rs = 0.f;
    #pragma unroll
    for (int cc = 0; cc < 8; ++cc) rs += __expf(Q[p * 8 + cc] - mr);
    qp[p] = __expf(Q[p * 8 + i] - mr) / rs;
  }
  float qself;
  {
    float mr = Q[j * 8 + 0];
    #pragma unroll
    for (int cc = 1; cc < 8; ++cc) mr = fmaxf(mr, Q[j * 8 + cc]);
    float rs = 0.f;
    #pragma unroll
    for (int cc = 0; cc < 8; ++cc) rs += __expf(Q[j * 8 + cc] - mr);
    qself = __expf(Q[j * 8 + i] - mr) / rs;
  }

  int t0 = 1 + c * 32;
  int L = (c == 15) ? 31 : 32;
  const float* evI = evT + (long)b * 4096 + (long)i * 512 + t0;

  float f[32];
  float accm = 0.f;
  #pragma unroll
  for (int s = 0; s < 32; ++s) {
    float e = (s < L) ? evI[s] : 0.f;
    float m = e;
    m = fmaxf(m, __shfl_xor(m, 8, 64));
    m = fmaxf(m, __shfl_xor(m, 16, 64));
    m = fmaxf(m, __shfl_xor(m, 32, 64));
    f[s] = __expf(e - m);
    if (s < L) accm += m;
  }

  float P = f[0] * qself;
  #pragma unroll
  for (int s = 1; s < 32; ++s) {
    if (s < L) {
      float a0 = __shfl(P, j,      64);
      float a1 = __shfl(P, 8 + j,  64);
      float a2 = __shfl(P, 16 + j, 64);
      float a3 = __shfl(P, 24 + j, 64);
      float a4 = __shfl(P, 32 + j, 64);
      float a5 = __shfl(P, 40 + j, 64);
      float a6 = __shfl(P, 48 + j, 64);
      float a7 = __shfl(P, 56 + j, 64);
      float sv = ((qp[0] * a0 + qp[1] * a1) + (qp[2] * a2 + qp[3] * a3))
               + ((qp[4] * a4 + qp[5] * a5) + (qp[6] * a6 + qp[7] * a7));
      P = f[s] * sv;
    }
    if ((s & 7) == 7) {
      float mx = P;
      mx = fmaxf(mx, __shfl_xor(mx, 1, 64));
      mx = fmaxf(mx, __shfl_xor(mx, 2, 64));
      mx = fmaxf(mx, __shfl_xor(mx, 4, 64));
      mx = fmaxf(mx, __shfl_xor(mx, 8, 64));
      mx = fmaxf(mx, __shfl_xor(mx, 16, 64));
      mx = fmaxf(mx, __shfl_xor(mx, 32, 64));
      mx = fmaxf(mx, 1e-30f);
      P = P / mx;
      accm += __logf(mx);
    }
  }
  pbuf[(long)job * 64 + lane] = P;
  if (lane == 0) accbuf[job] = accm;
}

__global__ __launch_bounds__(512) void hmm_comb(const float* __restrict__ pi,
                                                const float* __restrict__ evT,
                                                const float* __restrict__ pbuf,
                                                const float* __restrict__ accbuf,
                                                float* __restrict__ ws) {
  int tid = threadIdx.x;
  int wid = tid >> 6, lane = tid & 63;
  int b = blockIdx.x * 8 + wid;
  int j = lane & 7;

  float mp = pi[0];
  #pragma unroll
  for (int cc = 1; cc < 8; ++cc) mp = fmaxf(mp, pi[cc]);
  float sp = 0.f;
  #pragma unroll
  for (int cc = 0; cc < 8; ++cc) sp += __expf(pi[cc] - mp);
  float lpi = pi[j] - mp - __logf(sp);

  float lp0 = evT[(long)b * 4096 + (long)j * 512] + lpi;
  float m0 = lp0;
  m0 = fmaxf(m0, __shfl_xor(m0, 1, 64));
  m0 = fmaxf(m0, __shfl_xor(m0, 2, 64));
  m0 = fmaxf(m0, __shfl_xor(m0, 4, 64));
  float u = __expf(lp0 - m0);
  double acc = (double)m0;

  #pragma unroll
  for (int c = 0; c < 16; ++c) {
    float P = pbuf[((long)b * 16 + c) * 64 + lane];
    float contrib = P * u;
    contrib += __shfl_xor(contrib, 1, 64);
    contrib += __shfl_xor(contrib, 2, 64);
    contrib += __shfl_xor(contrib, 4, 64);
    u = __shfl(contrib, j * 9, 64);
    float mxu = u;
    mxu = fmaxf(mxu, __shfl_xor(mxu, 1, 64));
    mxu = fmaxf(mxu, __shfl_xor(mxu, 2, 64));
    mxu = fmaxf(mxu, __shfl_xor(mxu, 4, 64));
    mxu = fmaxf(mxu, 1e-30f);
    u = u / mxu;
    acc += (double)(__logf(mxu) + accbuf[b * 16 + c]);
  }
  float su = u;
  su += __shfl_xor(su, 1, 64);
  su += __shfl_xor(su, 2, 64);
  su += __shfl_xor(su, 4, 64);
  float logZ = (float)(acc + (double)__logf(su));
  if (lane == 0) atomicAdd(&ws[2], logZ);
}

// ---------------------------------------------------------------------------
// decoder (bf16 MFMA): x_hat = leaky(Z@Wd1+bd1)@Wd2+bd2 ; recon accumulation.
// 256 thr (4 waves), 128 rows/block, 256 blocks (1/CU).
// ---------------------------------------------------------------------------
__global__ __launch_bounds__(256) void dec_kernel(
    const float* __restrict__ x, const float* __restrict__ z,
    const float* __restrict__ Wd1, const float* __restrict__ bd1,
    const float* __restrict__ Wd2, const float* __restrict__ bd2,
    float* __restrict__ xhat, float* __restrict__ ws) {
  __shared__ __align__(16) unsigned short w1t[256 * 24];    // [n=hid][k=lat]
  __shared__ __align__(16) unsigned short w2t[128 * 264];   // [n=obs][k=hid]
  __shared__ __align__(16) unsigned short hbuf[4 * 16 * 264];
  __shared__ float sred;
  int tid = threadIdx.x;
  if (tid == 0) sred = 0.f;
  for (int e = tid; e < 4096; e += 256) {       // Wd1 [16][256]
    int k = e >> 8, n = e & 255;
    w1t[n * 24 + k] = f2bf(Wd1[e]);
  }
  for (int e = tid; e < 32768; e += 256) {      // Wd2 [256][128]
    int k = e >> 7, n = e & 127;
    w2t[n * 264 + k] = f2bf(Wd2[e]);
  }
  __syncthreads();

  int wid = tid >> 6, lane = tid & 63;
  int m = lane & 15, quad = lane >> 4;
  unsigned short* hb = hbuf + wid * (16 * 264);
  const float C0 = -0.5f * logf(6.2831853071795864f * VAR_F);
  float rsum = 0.f;

  #pragma unroll
  for (int tile = 0; tile < 2; ++tile) {
    long rowb = (long)blockIdx.x * 128 + wid * 32 + tile * 16;
    // A-frag from z (K=16 padded to 32)
    short8 za = (short8)0;
    if (quad < 2) {
      const float* zp = z + (rowb + m) * 16 + quad * 8;
      float4 f0 = *(const float4*)zp;
      float4 f1 = *(const float4*)(zp + 4);
      za[0] = (short)f2bf(f0.x); za[1] = (short)f2bf(f0.y);
      za[2] = (short)f2bf(f0.z); za[3] = (short)f2bf(f0.w);
      za[4] = (short)f2bf(f1.x); za[5] = (short)f2bf(f1.y);
      za[6] = (short)f2bf(f1.z); za[7] = (short)f2bf(f1.w);
    }
    // GEMM1 + leaky -> hb
    #pragma unroll 4
    for (int c = 0; c < 16; ++c) {
      short8 bfrag = (short8)0;
      if (quad < 2) bfrag = *(const short8*)&w1t[(c * 16 + m) * 24 + quad * 8];
      float bias = bd1[c * 16 + m];
      floatx4 a1 = {bias, bias, bias, bias};
      a1 = __builtin_amdgcn_mfma_f32_16x16x32_bf16(za, bfrag, a1, 0, 0, 0);
      #pragma unroll
      for (int g = 0; g < 4; ++g)
        hb[(quad * 4 + g) * 264 + c * 16 + m] = f2bf(leakyf(a1[g]));
    }
    // GEMM2: 8 col-tiles, ha reused across col-tiles
    floatx4 a2[8];
    #pragma unroll
    for (int c2 = 0; c2 < 8; ++c2) {
      float bv = bd2[c2 * 16 + m];
      a2[c2] = (floatx4){bv, bv, bv, bv};
    }
    #pragma unroll
    for (int kt = 0; kt < 8; ++kt) {
      short8 ha = *(const short8*)&hb[m * 264 + kt * 32 + quad * 8];
      #pragma unroll
      for (int c2 = 0; c2 < 8; ++c2) {
        short8 wb = *(const short8*)&w2t[(c2 * 16 + m) * 264 + kt * 32 + quad * 8];
        a2[c2] = __builtin_amdgcn_mfma_f32_16x16x32_bf16(ha, wb, a2[c2], 0, 0, 0);
      }
    }
    // epilogue: store x_hat, accumulate recon
    #pragma unroll
    for (int c2 = 0; c2 < 8; ++c2) {
      int col = c2 * 16 + m;
      #pragma unroll
      for (int g = 0; g < 4; ++g) {
        long row = rowb + quad * 4 + g;
        float xh = a2[c2][g];
        xhat[row * 128 + col] = xh;
        float dd = x[row * 128 + col] - xh;
        rsum += C0 - dd * dd * (0.5f / VAR_F);
      }
    }
  }
  #pragma unroll
  for (int off = 1; off < 64; off <<= 1) rsum += __shfl_xor(rsum, off, 64);
  if (lane == 0) atomicAdd(&sred, rsum);
  __syncthreads();
  if (tid == 0) atomicAdd(&ws[0], sred);
}

__global__ void fin_kernel(const float* __restrict__ ws, float* __restrict__ out) {
  float loss = -((ws[0] - ws[1] + ws[2]) * (1.f / 64.f));
  out[LOSS_OFF] = loss;
}

extern "C" void kernel_launch(void* const* d_in, const int* in_sizes, int n_in,
                              void* d_out, int out_size, void* d_ws, size_t ws_size,
                              hipStream_t stream) {
  (void)in_sizes; (void)n_in; (void)out_size; (void)ws_size;
  const float* x   = (const float*)d_in[0];
  const float* eps = (const float*)d_in[1];
  const float* W1  = (const float*)d_in[2];
  const float* b1  = (const float*)d_in[3];
  const float* W2  = (const float*)d_in[4];
  const float* b2  = (const float*)d_in[5];
  const float* Wt1 = (const float*)d_in[6];
  const float* bt1 = (const float*)d_in[7];
  const float* Wt2 = (const float*)d_in[8];
  const float* bt2 = (const float*)d_in[9];
  const float* Wd1 = (const float*)d_in[10];
  const float* bd1 = (const float*)d_in[11];
  const float* Wd2 = (const float*)d_in[12];
  const float* bd2 = (const float*)d_in[13];
  const float* Q   = (const float*)d_in[14];
  const float* pi  = (const float*)d_in[15];
  const float* im  = (const float*)d_in[16];
  const float* ic  = (const float*)d_in[17];
  const float* cv  = (const float*)d_in[18];
  float* out = (float*)d_out;
  float* ws  = (float*)d_ws;
  float* z_out = out + Z_OUT_OFF;
  float* evT  = out;             // staged in x_hat region, consumed before dec
  float* pbuf = out + PBUF_OFF;
  float* accb = out + ACC_OFF;

  hipMemsetAsync(ws, 0, 16, stream);
  prep_kernel<<<16, 256, 0, stream>>>(ic, cv, ws);
  enc_kernel<<<256, 256, 0, stream>>>(x, eps, W1, b1, W2, b2, z_out, ws);
  ev0_kernel<<<2, 256, 0, stream>>>(z_out, im, ws, evT);
  evt_kernel<<<dim3(512, 8), 256, 0, stream>>>(z_out, Wt1, bt1, Wt2, bt2, ws, evT);
  hmm_scan<<<256, 256, 0, stream>>>(Q, evT, pbuf, accb);
  hmm_comb<<<8, 512, 0, stream>>>(pi, evT, pbuf, accb, ws);
  dec_kernel<<<256, 256, 0, stream>>>(x, z_out, Wd1, bd1, Wd2, bd2, out, ws);
  fin_kernel<<<1, 1, 0, stream>>>(ws, out);
}

// Round 7
// 252.244 us; speedup vs baseline: 2.8399x; 1.0381x over previous
//
#include <hip/hip_runtime.h>
#include <math.h>

#define B_SZ   64
#define T_SZ   512
#define DOBS   128
#define DLAT   16
#define DHID   256
#define K_SZ   8
#define ROWS_A 32768   // B*T

#define LOG2PI_F 1.8378770664093453f
#define VAR_F    5.0e-4f

// ws float offsets
#define LINV0_OFF   16
#define LOGDET0_OFF 2064
#define LINVT_OFF   2080
#define LOGDETT_OFF 4128
// ws[0]=recon_sum ws[1]=logq_sum ws[2]=msm_sum
#define WIMG_F_OFF  8192      // bf16 weight images start here (ushort region)

// bf16 weight image offsets (in shorts, within wimg)
#define EVT_W1   0            // [k][i=256][d pad24]   <- Wt1[k][d][i]
#define EVT_W2   49152        // [k][d2=16][h pad264]  <- Wt2[k][h][d2]
#define EVT_LINV 82944        // [k][i=16][j pad24]    <- LinvT[k][i][j]
#define ENC_W1   86016        // [n=256][kk=128 pad136] <- W1[kk][n]
#define ENC_W2   120832       // [n=32][kk=256 pad264]  <- W2[kk][n]
#define DEC_W1   129280       // [n=256][kk=16 pad24]   <- Wd1[kk][n]
#define DEC_W2   135424       // [n=128][kk=256 pad264] <- Wd2[kk][n]
#define WCVT_TOTAL 141568     // logical (unpadded) element count

#define Z_OUT_OFF   4194304   // B*T*DOBS
#define LOSS_OFF    4718592   // + B*T*DLAT
// staging inside x_hat region of d_out (consumed before dec overwrites):
#define PBUF_OFF  262144
#define ACC_OFF   327680

typedef __attribute__((ext_vector_type(8))) short short8;
typedef __attribute__((ext_vector_type(8))) unsigned short ush8;
typedef __attribute__((ext_vector_type(4))) float floatx4;

__device__ __forceinline__ float leakyf(float v) { return v > 0.f ? v : 0.01f * v; }
__device__ __forceinline__ unsigned short f2bf(float f) {
  union { float f; unsigned int u; } v; v.f = f;
  unsigned int lsb = (v.u >> 16) & 1;
  v.u += 0x7fffu + lsb;   // round-to-nearest-even
  return (unsigned short)(v.u >> 16);
}

// ---------------------------------------------------------------------------
// prep: per-k Cholesky of C C^T + 1e-6 I, then Linv (lower-tri inverse), logdet.
// Also zeroes the ws accumulators (job 0).
// ---------------------------------------------------------------------------
__global__ __launch_bounds__(256) void prep_kernel(const float* __restrict__ init_cov,
                                                   const float* __restrict__ covs,
                                                   float* __restrict__ ws) {
  __shared__ float M[16][16];
  __shared__ float L[16][16];
  __shared__ float X[16][17];
  int job = blockIdx.x;
  const float* C = (job < 8) ? (init_cov + job * 256) : (covs + (job - 8) * 256);
  float* linv = ws + ((job < 8) ? (LINV0_OFF + job * 256) : (LINVT_OFF + (job - 8) * 256));
  float* logdet = ws + ((job < 8) ? (LOGDET0_OFF + job) : (LOGDETT_OFF + (job - 8)));
  int tid = threadIdx.x;
  if (job == 0 && tid < 4) ws[tid] = 0.f;
  int i = tid >> 4, j = tid & 15;
  {
    float s = (i == j) ? 1e-6f : 0.f;
    #pragma unroll
    for (int p = 0; p < 16; ++p) s += C[i * 16 + p] * C[j * 16 + p];
    M[i][j] = s;
  }
  __syncthreads();
  for (int c = 0; c < 16; ++c) {
    if (tid == 0) {
      float s = M[c][c];
      for (int p = 0; p < c; ++p) s -= L[c][p] * L[c][p];
      L[c][c] = sqrtf(s);
    }
    __syncthreads();
    if (tid > c && tid < 16) {
      float s = M[tid][c];
      for (int p = 0; p < c; ++p) s -= L[tid][p] * L[c][p];
      L[tid][c] = s / L[c][c];
    }
    __syncthreads();
  }
  if (tid < 16) {
    for (int r = 0; r < 16; ++r) {
      float s = (r == tid) ? 1.f : 0.f;
      for (int p = tid; p < r; ++p) s -= L[r][p] * X[p][tid];
      X[r][tid] = (r >= tid) ? s / L[r][r] : 0.f;
    }
  }
  __syncthreads();
  linv[i * 16 + j] = X[i][j];
  if (tid == 0) {
    float s = 0.f;
    for (int d = 0; d < 16; ++d) s += logf(L[d][d]);
    *logdet = 2.f * s;
  }
}

// ---------------------------------------------------------------------------
// wcvt: one-time fp32 -> bf16 weight-image conversion (frag-ready layouts).
// Must run after prep (needs LinvT). Pads are never read -> left garbage.
// ---------------------------------------------------------------------------
__global__ __launch_bounds__(256) void wcvt_kernel(
    const float* __restrict__ Wt1, const float* __restrict__ Wt2,
    const float* __restrict__ W1, const float* __restrict__ W2,
    const float* __restrict__ Wd1, const float* __restrict__ Wd2,
    const float* __restrict__ ws, unsigned short* __restrict__ wimg) {
  for (int e = blockIdx.x * 256 + threadIdx.x; e < WCVT_TOTAL; e += gridDim.x * 256) {
    if (e < 32768) {                       // EVT_W1
      int k = e >> 12, r = e & 4095, i = r >> 4, d = r & 15;
      wimg[EVT_W1 + k * 6144 + i * 24 + d] = f2bf(Wt1[k * 4096 + d * 256 + i]);
    } else if (e < 65536) {                // EVT_W2
      int e2 = e - 32768; int k = e2 >> 12, r = e2 & 4095, h = r >> 4, d2 = r & 15;
      wimg[EVT_W2 + k * 4224 + d2 * 264 + h] = f2bf(Wt2[k * 4096 + h * 16 + d2]);
    } else if (e < 67584) {                // EVT_LINV
      int e2 = e - 65536; int k = e2 >> 8, r = e2 & 255, i = r >> 4, j = r & 15;
      wimg[EVT_LINV + k * 384 + i * 24 + j] = f2bf(ws[LINVT_OFF + k * 256 + i * 16 + j]);
    } else if (e < 100352) {               // ENC_W1
      int e2 = e - 67584; int n = e2 >> 7, kk = e2 & 127;
      wimg[ENC_W1 + n * 136 + kk] = f2bf(W1[kk * 256 + n]);
    } else if (e < 108544) {               // ENC_W2
      int e2 = e - 100352; int n = e2 >> 8, kk = e2 & 255;
      wimg[ENC_W2 + n * 264 + kk] = f2bf(W2[kk * 32 + n]);
    } else if (e < 112640) {               // DEC_W1
      int e2 = e - 108544; int n = e2 >> 4, kk = e2 & 15;
      wimg[DEC_W1 + n * 24 + kk] = f2bf(Wd1[kk * 256 + n]);
    } else {                               // DEC_W2
      int e2 = e - 112640; int n = e2 & 127, kk = e2 >> 7;
      wimg[DEC_W2 + n * 264 + kk] = f2bf(Wd2[kk * 128 + n]);
    }
  }
}

// ---------------------------------------------------------------------------
// encoder (bf16 MFMA, interleaved): per 16-row tile,
// GEMM1 col-pair -> leaky -> per-wave 16x32 LDS transpose tile -> GEMM2.
// W1 B-frags read from global image (L2-hot). 512 blocks x 64 rows.
// ---------------------------------------------------------------------------
__global__ __launch_bounds__(256) void enc_kernel(
    const float* __restrict__ x, const float* __restrict__ eps,
    const float* __restrict__ b1, const float* __restrict__ b2,
    const unsigned short* __restrict__ wimg,
    float* __restrict__ z_out, float* __restrict__ ws) {
  __shared__ __align__(16) unsigned short w2t[32 * 264];
  __shared__ __align__(16) unsigned short ttile[4][16 * 56];
  __shared__ float b1s[256];
  __shared__ float sred;
  int tid = threadIdx.x;
  if (tid == 0) sred = 0.f;
  {
    const ush8* s2 = (const ush8*)(wimg + ENC_W2);
    for (int e = tid; e < 1056; e += 256) ((ush8*)w2t)[e] = s2[e];
    b1s[tid] = b1[tid];
  }
  __syncthreads();

  int wid = tid >> 6, lane = tid & 63;
  int m = lane & 15, quad = lane >> 4;
  unsigned short* tt = ttile[wid];
  const unsigned short* w1i = wimg + ENC_W1;
  long rowb = (long)blockIdx.x * 64 + wid * 16;

  // A-frags from x
  short8 xa[4];
  const float* xp = x + (rowb + m) * 128 + quad * 8;
  #pragma unroll
  for (int kt = 0; kt < 4; ++kt) {
    float4 f0 = *(const float4*)(xp + kt * 32);
    float4 f1 = *(const float4*)(xp + kt * 32 + 4);
    short8 v;
    v[0] = (short)f2bf(f0.x); v[1] = (short)f2bf(f0.y);
    v[2] = (short)f2bf(f0.z); v[3] = (short)f2bf(f0.w);
    v[4] = (short)f2bf(f1.x); v[5] = (short)f2bf(f1.y);
    v[6] = (short)f2bf(f1.z); v[7] = (short)f2bf(f1.w);
    xa[kt] = v;
  }
  float bm0 = b2[m], bm1 = b2[16 + m];
  floatx4 a20 = {bm0, bm0, bm0, bm0};
  floatx4 a21 = {bm1, bm1, bm1, bm1};
  #pragma unroll
  for (int cp = 0; cp < 8; ++cp) {
    #pragma unroll
    for (int h = 0; h < 2; ++h) {
      int c = cp * 2 + h;
      float bias = b1s[c * 16 + m];
      floatx4 a1 = {bias, bias, bias, bias};
      #pragma unroll
      for (int kt = 0; kt < 4; ++kt) {
        short8 bf = *(const short8*)&w1i[(c * 16 + m) * 136 + kt * 32 + quad * 8];
        a1 = __builtin_amdgcn_mfma_f32_16x16x32_bf16(xa[kt], bf, a1, 0, 0, 0);
      }
      #pragma unroll
      for (int g = 0; g < 4; ++g)
        tt[(quad * 4 + g) * 56 + h * 16 + m] = f2bf(leakyf(a1[g]));
    }
    short8 ha = *(const short8*)&tt[m * 56 + quad * 8];
    short8 wb0 = *(const short8*)&w2t[m * 264 + cp * 32 + quad * 8];
    short8 wb1 = *(const short8*)&w2t[(16 + m) * 264 + cp * 32 + quad * 8];
    a20 = __builtin_amdgcn_mfma_f32_16x16x32_bf16(ha, wb0, a20, 0, 0, 0);
    a21 = __builtin_amdgcn_mfma_f32_16x16x32_bf16(ha, wb1, a21, 0, 0, 0);
  }
  // epilogue: z + logq
  float logq_acc = 0.f;
  #pragma unroll
  for (int g = 0; g < 4; ++g) {
    long row = rowb + quad * 4 + g;
    float mu = a20[g], lv = a21[g];
    float ev = eps[row * 16 + m];
    float zv = mu + __expf(0.5f * lv) * ev;
    z_out[row * 16 + m] = zv;
    float zz = zv - mu;
    logq_acc += lv + zz * zz * __expf(-lv);
  }
  #pragma unroll
  for (int off = 1; off < 64; off <<= 1) logq_acc += __shfl_xor(logq_acc, off, 64);
  if (lane == 0) atomicAdd(&sred, -0.5f * logq_acc);
  __syncthreads();
  if (tid == 0) atomicAdd(&ws[1], sred - 0.5f * 16.f * LOG2PI_F * 64.f);
}

// ---------------------------------------------------------------------------
// evt (bf16 MFMA, interleaved): per k, 256 rows/block, 4 tiles/wave.
// Weights staged from bf16 images via pure vector copies.
// ---------------------------------------------------------------------------
__global__ __launch_bounds__(256) void evt_kernel(
    const float* __restrict__ z, const unsigned short* __restrict__ wimg,
    const float* __restrict__ bt1, const float* __restrict__ bt2,
    const float* __restrict__ ws, float* __restrict__ evT) {
  __shared__ __align__(16) unsigned short w1t[6144];    // [i=256][d pad24]
  __shared__ __align__(16) unsigned short w2t[4224];    // [d2=16][h pad264]
  __shared__ __align__(16) unsigned short linvb[384];   // [i=16][j pad24]
  __shared__ __align__(16) unsigned short ttile[4][16 * 56];
  __shared__ __align__(16) unsigned short dtile[4][16 * 24];
  __shared__ float bt1s[256];
  int tid = threadIdx.x;
  int k = blockIdx.y;
  {
    const ush8* s1 = (const ush8*)(wimg + EVT_W1 + k * 6144);
    for (int e = tid; e < 768; e += 256) ((ush8*)w1t)[e] = s1[e];
    const ush8* s2 = (const ush8*)(wimg + EVT_W2 + k * 4224);
    for (int e = tid; e < 528; e += 256) ((ush8*)w2t)[e] = s2[e];
    if (tid < 48) ((ush8*)linvb)[tid] = ((const ush8*)(wimg + EVT_LINV + k * 384))[tid];
    bt1s[tid] = bt1[k * 256 + tid];
  }
  float logdetk = ws[LOGDETT_OFF + k];
  __syncthreads();

  int wid = tid >> 6, lane = tid & 63;
  int m = lane & 15, quad = lane >> 4;
  unsigned short* tt = ttile[wid];
  unsigned short* db = dtile[wid];
  float btv = bt2[k * 16 + m];

  #pragma unroll
  for (int tile = 0; tile < 4; ++tile) {
    long rowb = (long)blockIdx.x * 256 + wid * 64 + tile * 16;
    short8 za = (short8)0;
    if (quad < 2) {
      const float* zp = z + (rowb + m) * 16 + quad * 8;
      float4 f0 = *(const float4*)zp;
      float4 f1 = *(const float4*)(zp + 4);
      za[0] = (short)f2bf(f0.x); za[1] = (short)f2bf(f0.y);
      za[2] = (short)f2bf(f0.z); za[3] = (short)f2bf(f0.w);
      za[4] = (short)f2bf(f1.x); za[5] = (short)f2bf(f1.y);
      za[6] = (short)f2bf(f1.z); za[7] = (short)f2bf(f1.w);
    }
    floatx4 a2 = {btv, btv, btv, btv};
    #pragma unroll
    for (int cp = 0; cp < 8; ++cp) {
      #pragma unroll
      for (int h = 0; h < 2; ++h) {
        int c = cp * 2 + h;
        short8 bfrag = (short8)0;
        if (quad < 2) bfrag = *(const short8*)&w1t[(c * 16 + m) * 24 + quad * 8];
        float bias = bt1s[c * 16 + m];
        floatx4 a1 = {bias, bias, bias, bias};
        a1 = __builtin_amdgcn_mfma_f32_16x16x32_bf16(za, bfrag, a1, 0, 0, 0);
        #pragma unroll
        for (int g = 0; g < 4; ++g) {
          float v = a1[g];
          float t = __expf(-fabsf(v));
          float sp = fmaxf(v, 0.f) + __logf(1.f + t);
          tt[(quad * 4 + g) * 56 + h * 16 + m] = f2bf(sp);
        }
      }
      short8 ha = *(const short8*)&tt[m * 56 + quad * 8];
      short8 wb = *(const short8*)&w2t[m * 264 + cp * 32 + quad * 8];
      a2 = __builtin_amdgcn_mfma_f32_16x16x32_bf16(ha, wb, a2, 0, 0, 0);
    }
    // diff -> dtile -> GEMM3 vs Linv^T
    #pragma unroll
    for (int g = 0; g < 4; ++g) {
      long grow = rowb + quad * 4 + g;
      float znx = (grow + 1 < ROWS_A) ? z[(grow + 1) * 16 + m] : 0.f;
      db[(quad * 4 + g) * 24 + m] = f2bf(znx - a2[g]);
    }
    short8 da = (short8)0, lb = (short8)0;
    if (quad < 2) {
      da = *(const short8*)&db[m * 24 + quad * 8];
      lb = *(const short8*)&linvb[m * 24 + quad * 8];
    }
    floatx4 a3 = {0.f, 0.f, 0.f, 0.f};
    a3 = __builtin_amdgcn_mfma_f32_16x16x32_bf16(da, lb, a3, 0, 0, 0);
    #pragma unroll
    for (int g = 0; g < 4; ++g) {
      float v = a3[g];
      v = v * v;
      v += __shfl_xor(v, 1, 64);
      v += __shfl_xor(v, 2, 64);
      v += __shfl_xor(v, 4, 64);
      v += __shfl_xor(v, 8, 64);
      long grow = rowb + quad * 4 + g;
      if (m == 0 && (grow & 511) != 511) {
        long r1 = grow + 1;
        evT[(r1 >> 9) * 4096 + (long)k * 512 + (r1 & 511)] =
            -0.5f * (16.f * LOG2PI_F + logdetk + v);
      }
    }
  }
}

// ---------------------------------------------------------------------------
// HMM forward as a parallel scan over 8x8 transition matrices (see r5 notes).
// ---------------------------------------------------------------------------
__global__ __launch_bounds__(256) void hmm_scan(const float* __restrict__ Q,
                                                const float* __restrict__ evT,
                                                float* __restrict__ pbuf,
                                                float* __restrict__ accbuf) {
  int tid = threadIdx.x;
  int wid = tid >> 6, lane = tid & 63;
  int job = blockIdx.x * 4 + wid;
  int b = job >> 4, c = job & 15;
  int i = lane >> 3, j = lane & 7;

  float qp[8];
  #pragma unroll
  for (int p = 0; p < 8; ++p) {
    float mr = Q[p * 8 + 0];
    #pragma unroll
    for (int cc = 1; cc < 8; ++cc) mr = fmaxf(mr, Q[p * 8 + cc]);
    float rs = 0.f;
    #pragma unroll
    for (int cc = 0; cc < 8; ++cc) rs += __expf(Q[p * 8 + cc] - mr);
    qp[p] = __expf(Q[p * 8 + i] - mr) / rs;
  }
  float qself;
  {
    float mr = Q[j * 8 + 0];
    #pragma unroll
    for (int cc = 1; cc < 8; ++cc) mr = fmaxf(mr, Q[j * 8 + cc]);
    float rs = 0.f;
    #pragma unroll
    for (int cc = 0; cc < 8; ++cc) rs += __expf(Q[j * 8 + cc] - mr);
    qself = __expf(Q[j * 8 + i] - mr) / rs;
  }

  int t0 = 1 + c * 32;
  int L = (c == 15) ? 31 : 32;
  const float* evI = evT + (long)b * 4096 + (long)i * 512 + t0;

  float f[32];
  float accm = 0.f;
  #pragma unroll
  for (int s = 0; s < 32; ++s) {
    float e = (s < L) ? evI[s] : 0.f;
    float m = e;
    m = fmaxf(m, __shfl_xor(m, 8, 64));
    m = fmaxf(m, __shfl_xor(m, 16, 64));
    m = fmaxf(m, __shfl_xor(m, 32, 64));
    f[s] = __expf(e - m);
    if (s < L) accm += m;
  }

  float P = f[0] * qself;
  #pragma unroll
  for (int s = 1; s < 32; ++s) {
    if (s < L) {
      float a0 = __shfl(P, j,      64);
      float a1 = __shfl(P, 8 + j,  64);
      float a2 = __shfl(P, 16 + j, 64);
      float a3 = __shfl(P, 24 + j, 64);
      float a4 = __shfl(P, 32 + j, 64);
      float a5 = __shfl(P, 40 + j, 64);
      float a6 = __shfl(P, 48 + j, 64);
      float a7 = __shfl(P, 56 + j, 64);
      float sv = ((qp[0] * a0 + qp[1] * a1) + (qp[2] * a2 + qp[3] * a3))
               + ((qp[4] * a4 + qp[5] * a5) + (qp[6] * a6 + qp[7] * a7));
      P = f[s] * sv;
    }
    if ((s & 7) == 7) {
      float mx = P;
      mx = fmaxf(mx, __shfl_xor(mx, 1, 64));
      mx = fmaxf(mx, __shfl_xor(mx, 2, 64));
      mx = fmaxf(mx, __shfl_xor(mx, 4, 64));
      mx = fmaxf(mx, __shfl_xor(mx, 8, 64));
      mx = fmaxf(mx, __shfl_xor(mx, 16, 64));
      mx = fmaxf(mx, __shfl_xor(mx, 32, 64));
      mx = fmaxf(mx, 1e-30f);
      P = P / mx;
      accm += __logf(mx);
    }
  }
  pbuf[(long)job * 64 + lane] = P;
  if (lane == 0) accbuf[job] = accm;
}

// ---------------------------------------------------------------------------
// Stage 2: fold chunks; ev0 (t=0 mvn) computed inline. One wave per batch.
// ---------------------------------------------------------------------------
__global__ __launch_bounds__(512) void hmm_comb(const float* __restrict__ pi,
                                                const float* __restrict__ z,
                                                const float* __restrict__ init_mean,
                                                const float* __restrict__ pbuf,
                                                const float* __restrict__ accbuf,
                                                float* __restrict__ ws) {
  int tid = threadIdx.x;
  int wid = tid >> 6, lane = tid & 63;
  int b = blockIdx.x * 8 + wid;
  int j = lane & 7;

  float mp = pi[0];
  #pragma unroll
  for (int cc = 1; cc < 8; ++cc) mp = fmaxf(mp, pi[cc]);
  float sp = 0.f;
  #pragma unroll
  for (int cc = 0; cc < 8; ++cc) sp += __expf(pi[cc] - mp);
  float lpi = pi[j] - mp - __logf(sp);

  // ev0(b, k=j) inline
  const float* zr = z + (long)b * 8192;
  const float* linv = ws + LINV0_OFF + j * 256;
  float diff[16];
  #pragma unroll
  for (int d = 0; d < 16; ++d) diff[d] = zr[d] - init_mean[j * 16 + d];
  float quad0 = 0.f;
  #pragma unroll
  for (int i2 = 0; i2 < 16; ++i2) {
    float s = 0.f;
    #pragma unroll
    for (int jj = 0; jj < 16; ++jj) s += linv[i2 * 16 + jj] * diff[jj];
    quad0 += s * s;
  }
  float ev0 = -0.5f * (16.f * LOG2PI_F + ws[LOGDET0_OFF + j] + quad0);

  float lp0 = ev0 + lpi;
  float m0 = lp0;
  m0 = fmaxf(m0, __shfl_xor(m0, 1, 64));
  m0 = fmaxf(m0, __shfl_xor(m0, 2, 64));
  m0 = fmaxf(m0, __shfl_xor(m0, 4, 64));
  float u = __expf(lp0 - m0);
  double acc = (double)m0;

  #pragma unroll
  for (int c = 0; c < 16; ++c) {
    float P = pbuf[((long)b * 16 + c) * 64 + lane];
    float contrib = P * u;
    contrib += __shfl_xor(contrib, 1, 64);
    contrib += __shfl_xor(contrib, 2, 64);
    contrib += __shfl_xor(contrib, 4, 64);
    u = __shfl(contrib, j * 9, 64);
    float mxu = u;
    mxu = fmaxf(mxu, __shfl_xor(mxu, 1, 64));
    mxu = fmaxf(mxu, __shfl_xor(mxu, 2, 64));
    mxu = fmaxf(mxu, __shfl_xor(mxu, 4, 64));
    mxu = fmaxf(mxu, 1e-30f);
    u = u / mxu;
    acc += (double)(__logf(mxu) + accbuf[b * 16 + c]);
  }
  float su = u;
  su += __shfl_xor(su, 1, 64);
  su += __shfl_xor(su, 2, 64);
  su += __shfl_xor(su, 4, 64);
  float logZ = (float)(acc + (double)__logf(su));
  if (lane == 0) atomicAdd(&ws[2], logZ);
}

// ---------------------------------------------------------------------------
// decoder (bf16 MFMA, interleaved): 512 blocks x 64 rows.
// Wd2 B-frags from global image; Wd1 staged to LDS.
// ---------------------------------------------------------------------------
__global__ __launch_bounds__(256) void dec_kernel(
    const float* __restrict__ x, const float* __restrict__ z,
    const float* __restrict__ bd1, const float* __restrict__ bd2,
    const unsigned short* __restrict__ wimg,
    float* __restrict__ xhat, float* __restrict__ ws) {
  __shared__ __align__(16) unsigned short w1t[6144];
  __shared__ __align__(16) unsigned short ttile[4][16 * 56];
  __shared__ float bd1s[256];
  __shared__ float bd2s[128];
  __shared__ float sred;
  int tid = threadIdx.x;
  if (tid == 0) sred = 0.f;
  {
    const ush8* s1 = (const ush8*)(wimg + DEC_W1);
    for (int e = tid; e < 768; e += 256) ((ush8*)w1t)[e] = s1[e];
    bd1s[tid] = bd1[tid];
    if (tid < 128) bd2s[tid] = bd2[tid];
  }
  __syncthreads();

  int wid = tid >> 6, lane = tid & 63;
  int m = lane & 15, quad = lane >> 4;
  unsigned short* tt = ttile[wid];
  const unsigned short* w2i = wimg + DEC_W2;
  long rowb = (long)blockIdx.x * 64 + wid * 16;

  short8 za = (short8)0;
  if (quad < 2) {
    const float* zp = z + (rowb + m) * 16 + quad * 8;
    float4 f0 = *(const float4*)zp;
    float4 f1 = *(const float4*)(zp + 4);
    za[0] = (short)f2bf(f0.x); za[1] = (short)f2bf(f0.y);
    za[2] = (short)f2bf(f0.z); za[3] = (short)f2bf(f0.w);
    za[4] = (short)f2bf(f1.x); za[5] = (short)f2bf(f1.y);
    za[6] = (short)f2bf(f1.z); za[7] = (short)f2bf(f1.w);
  }
  floatx4 a2[8];
  #pragma unroll
  for (int c2 = 0; c2 < 8; ++c2) {
    float bv = bd2s[c2 * 16 + m];
    a2[c2] = (floatx4){bv, bv, bv, bv};
  }
  #pragma unroll
  for (int cp = 0; cp < 8; ++cp) {
    #pragma unroll
    for (int h = 0; h < 2; ++h) {
      int c = cp * 2 + h;
      short8 bfrag = (short8)0;
      if (quad < 2) bfrag = *(const short8*)&w1t[(c * 16 + m) * 24 + quad * 8];
      float bias = bd1s[c * 16 + m];
      floatx4 a1 = {bias, bias, bias, bias};
      a1 = __builtin_amdgcn_mfma_f32_16x16x32_bf16(za, bfrag, a1, 0, 0, 0);
      #pragma unroll
      for (int g = 0; g < 4; ++g)
        tt[(quad * 4 + g) * 56 + h * 16 + m] = f2bf(leakyf(a1[g]));
    }
    short8 ha = *(const short8*)&tt[m * 56 + quad * 8];
    #pragma unroll
    for (int c2 = 0; c2 < 8; ++c2) {
      short8 wb = *(const short8*)&w2i[(c2 * 16 + m) * 264 + cp * 32 + quad * 8];
      a2[c2] = __builtin_amdgcn_mfma_f32_16x16x32_bf16(ha, wb, a2[c2], 0, 0, 0);
    }
  }
  const float C0 = -0.5f * logf(6.2831853071795864f * VAR_F);
  float rsum = 0.f;
  #pragma unroll
  for (int c2 = 0; c2 < 8; ++c2) {
    int col = c2 * 16 + m;
    #pragma unroll
    for (int g = 0; g < 4; ++g) {
      long row = rowb + quad * 4 + g;
      float xh = a2[c2][g];
      xhat[row * 128 + col] = xh;
      float dd = x[row * 128 + col] - xh;
      rsum += C0 - dd * dd * (0.5f / VAR_F);
    }
  }
  #pragma unroll
  for (int off = 1; off < 64; off <<= 1) rsum += __shfl_xor(rsum, off, 64);
  if (lane == 0) atomicAdd(&sred, rsum);
  __syncthreads();
  if (tid == 0) atomicAdd(&ws[0], sred);
}

__global__ void fin_kernel(const float* __restrict__ ws, float* __restrict__ out) {
  float loss = -((ws[0] - ws[1] + ws[2]) * (1.f / 64.f));
  out[LOSS_OFF] = loss;
}

extern "C" void kernel_launch(void* const* d_in, const int* in_sizes, int n_in,
                              void* d_out, int out_size, void* d_ws, size_t ws_size,
                              hipStream_t stream) {
  (void)in_sizes; (void)n_in; (void)out_size; (void)ws_size;
  const float* x   = (const float*)d_in[0];
  const float* eps = (const float*)d_in[1];
  const float* W1  = (const float*)d_in[2];
  const float* b1  = (const float*)d_in[3];
  const float* W2  = (const float*)d_in[4];
  const float* b2  = (const float*)d_in[5];
  const float* Wt1 = (const float*)d_in[6];
  const float* bt1 = (const float*)d_in[7];
  const float* Wt2 = (const float*)d_in[8];
  const float* bt2 = (const float*)d_in[9];
  const float* Wd1 = (const float*)d_in[10];
  const float* bd1 = (const float*)d_in[11];
  const float* Wd2 = (const float*)d_in[12];
  const float* bd2 = (const float*)d_in[13];
  const float* Q   = (const float*)d_in[14];
  const float* pi  = (const float*)d_in[15];
  const float* im  = (const float*)d_in[16];
  const float* ic  = (const float*)d_in[17];
  const float* cv  = (const float*)d_in[18];
  float* out = (float*)d_out;
  float* ws  = (float*)d_ws;
  float* z_out = out + Z_OUT_OFF;
  float* evT  = out;             // staged in x_hat region, consumed before dec
  float* pbuf = out + PBUF_OFF;
  float* accb = out + ACC_OFF;
  unsigned short* wimg = (unsigned short*)(ws + WIMG_F_OFF);

  prep_kernel<<<16, 256, 0, stream>>>(ic, cv, ws);
  wcvt_kernel<<<144, 256, 0, stream>>>(Wt1, Wt2, W1, W2, Wd1, Wd2, ws, wimg);
  enc_kernel<<<512, 256, 0, stream>>>(x, eps, b1, b2, wimg, z_out, ws);
  evt_kernel<<<dim3(128, 8), 256, 0, stream>>>(z_out, wimg, bt1, bt2, ws, evT);
  hmm_scan<<<256, 256, 0, stream>>>(Q, evT, pbuf, accb);
  hmm_comb<<<8, 512, 0, stream>>>(pi, z_out, im, pbuf, accb, ws);
  dec_kernel<<<512, 256, 0, stream>>>(x, z_out, bd1, bd2, wimg, out, ws);
  fin_kernel<<<1, 1, 0, stream>>>(ws, out);
}